// Round 17
// baseline (218.981 us; speedup 1.0000x reference)
//
#include <hip/hip_runtime.h>
#include <math.h>

#define B_   2
#define N_   6
#define C_   64
#define D_   64
#define FH_  16
#define FW_  44
#define BN_  (B_*N_)              // 12
#define PIX_ (FH_*FW_)            // 704
#define NPIX (BN_*PIX_)           // 8448
#define NPTS (BN_*D_*PIX_)        // 540672
#define PPBN (D_*PIX_)            // 45056 points per (b,n) image
#define BEVH 200
#define BEVW 200
#define NCELL (BEVH*BEVW)         // 40000
#define NBCELL (B_*NCELL)         // 80000
#define NSCANB ((NBCELL + 255)/256)  // 313 scan blocks
#define PPW  64                   // points per wave in gather (staged in regs)
#define GBLK (NPTS/(PPW*4))       // 2112 gather blocks (4 waves each)
// record pack: pixg (14 bits, max 8447) | fc << 14 (17 bits, max 79999) -> <2^31

// setup mega-kernel block ranges
#define NB_ZOUT 5000              // out zero: 5.12M f32 = 1.28M float4
#define NB_ZSP  313               // startp zero (80001 ints)
#define NB_TW   160               // weight transposes (40960 elems)
#define NB_PREP 1                 // BN affine + Kinv
#define NB_FT   132               // feat transpose
#define NB_SETUP (NB_ZOUT + NB_ZSP + NB_TW + NB_PREP + NB_FT)   // 5606

// ---------------- setup: zero out + zero startp + transW + prep + featT -----
// w1t layout (for b128 enc reads): [cin-chunk(4)][tap(9)][cout(64)][cin%16]
__global__ __launch_bounds__(256) void setup_kernel(
        const float* __restrict__ feat, const float* __restrict__ w1,
        const float* __restrict__ w2,
        const float* __restrict__ gamma, const float* __restrict__ beta,
        const float* __restrict__ rmean, const float* __restrict__ rvar,
        const float* __restrict__ intr,
        float* __restrict__ out, int* __restrict__ startp,
        float* __restrict__ w1t, float* __restrict__ w2t,
        float* __restrict__ bns, float* __restrict__ bnsh,
        float* __restrict__ kinv, float* __restrict__ feat_t) {
#pragma clang fp contract(off)
    __shared__ float lds[64][65];
    int blk = blockIdx.x;
    int t   = threadIdx.x;

    if (blk < NB_ZOUT) {
        ((float4*)out)[blk*256 + t] = float4{0.f, 0.f, 0.f, 0.f};
        return;
    }
    blk -= NB_ZOUT;
    if (blk < NB_ZSP) {
        int i = blk*256 + t;
        if (i < NBCELL + 1) startp[i] = 0;
        return;
    }
    blk -= NB_ZSP;
    if (blk < NB_TW) {
        int idx = blk*256 + t;
        if (idx < C_*C_*9) {
            int cout = idx / (C_*9);
            int r    = idx % (C_*9);
            int cin  = r / 9;
            int tap  = r % 9;
            w1t[(((cin >> 4)*9 + tap)*64 + cout)*16 + (cin & 15)] = w1[idx];
        } else if (idx < C_*C_*9 + D_*C_) {
            int j = idx - C_*C_*9;
            int d = j / C_, c = j % C_;
            w2t[c*D_ + d] = w2[j];
        }
        return;
    }
    blk -= NB_TW;
    if (blk < NB_PREP) {
        if (t < C_) {
            float s = gamma[t] / sqrtf(rvar[t] + 1e-5f);
            bns[t]  = s;
            bnsh[t] = beta[t] - rmean[t] * s;
        }
        if (t < BN_) {
            const float* K = intr + t*9;
            float A[3][3];
            for (int r = 0; r < 3; r++)
                for (int cc = 0; cc < 3; cc++) A[r][cc] = K[r*3 + cc];
            int ipiv[3];
            // sgetf2
            for (int j = 0; j < 3; j++) {
                int p = j; float mx = fabsf(A[j][j]);
                for (int i = j+1; i < 3; i++) {
                    float v = fabsf(A[i][j]);
                    if (v > mx) { mx = v; p = i; }
                }
                ipiv[j] = p;
                if (p != j)
                    for (int k = 0; k < 3; k++) { float tm = A[j][k]; A[j][k] = A[p][k]; A[p][k] = tm; }
                float rpiv = 1.0f / A[j][j];
                for (int i = j+1; i < 3; i++) A[i][j] = A[i][j] * rpiv;
                for (int k = j+1; k < 3; k++)
                    for (int i = j+1; i < 3; i++)
                        A[i][k] = A[i][k] - A[i][j] * A[j][k];
            }
            // strti2
            for (int j = 0; j < 3; j++) {
                float ajj = 1.0f / A[j][j];
                A[j][j] = ajj;
                float najj = -ajj;
                for (int jj = 0; jj < j; jj++) {
                    float temp = A[jj][j];
                    for (int i = 0; i < jj; i++) A[i][j] = A[i][j] + temp * A[i][jj];
                    A[jj][j] = A[jj][j] * A[jj][jj];
                }
                for (int i = 0; i < j; i++) A[i][j] = A[i][j] * najj;
            }
            // sgetri
            for (int j = 1; j >= 0; j--) {
                float work[3];
                for (int i = j+1; i < 3; i++) { work[i] = A[i][j]; A[i][j] = 0.0f; }
                for (int k = j+1; k < 3; k++)
                    for (int i = 0; i < 3; i++)
                        A[i][j] = A[i][j] - A[i][k] * work[k];
            }
            for (int j = 2; j >= 0; j--) {
                int p = ipiv[j];
                if (p != j)
                    for (int i = 0; i < 3; i++) { float tm = A[i][j]; A[i][j] = A[i][p]; A[i][p] = tm; }
            }
            for (int k = 0; k < 9; k++) kinv[t*9 + k] = A[k/3][k%3];
        }
        return;
    }
    blk -= NB_PREP;
    // featT: [bn][c][pix] -> [bn*704+pix][c]
    {
        int bn   = blk / 11;
        int pb   = (blk % 11) * 64;
        int lane = t & 63;
        int r0   = t >> 6;
#pragma unroll
        for (int rr = 0; rr < 16; rr++) {
            int c = r0 + 4*rr;
            lds[c][lane] = feat[((size_t)bn*C_ + c)*PIX_ + pb + lane];
        }
        __syncthreads();
#pragma unroll
        for (int rr = 0; rr < 16; rr++) {
            int pr = r0 + 4*rr;
            feat_t[((size_t)bn*PIX_ + pb + pr)*C_ + lane] = lds[lane][pr];
        }
    }
}

// ---------------- enc v5: b128 LDS reads (4-ci weight/feature vectors) ------
__global__ __launch_bounds__(256) void enc_kernel(
        const float* __restrict__ feat_t,
        const float* __restrict__ w1t, const float* __restrict__ w2t,
        const float* __restrict__ bns, const float* __restrict__ bnsh,
        const float* __restrict__ b1,  const float* __restrict__ b2,
        float* __restrict__ probs) {
    __shared__ float wlds[9*C_*16];    // 36 KB: one 16-ci weight chunk
    __shared__ float flds[36][C_];     // 9 KB: 6x6 pixel window x 64 chan
    __shared__ float hl[16][C_];       // 4 KB
    int blk = blockIdx.x;              // 0..527
    int bn  = blk / 44;
    int rem = blk % 44;
    int yt  = rem / 11;
    int xt  = rem % 11;
    int t   = threadIdx.x;
    int c   = t & 63;
    int w   = __builtin_amdgcn_readfirstlane(t >> 6);   // wave id 0..3
    int y0  = yt*4;
    int x0  = xt*4;
    int y   = y0 + w;

    // stage feature window (zero-padded halo), coalesced from feat_t
    for (int s = w; s < 36; s += 4) {
        int srow = s / 6, scol = s % 6;
        int grow = y0 - 1 + srow;
        int gcol = x0 - 1 + scol;
        float v = 0.f;
        if (grow >= 0 && grow < FH_ && gcol >= 0 && gcol < FW_)
            v = feat_t[((size_t)bn*PIX_ + grow*FW_ + gcol)*C_ + c];
        flds[s][c] = v;
    }

    float h0 = b1[c], h1 = h0, h2 = h0, h3 = h0;

    for (int cc16 = 0; cc16 < 4; cc16++) {
        __syncthreads();               // covers flds (1st iter) + wlds reuse
        {
            const float4* s4 = (const float4*)(w1t + cc16*(9*C_*16));
            float4* d4 = (float4*)wlds;
#pragma unroll
            for (int i = 0; i < 9; i++)
                d4[t + 256*i] = s4[t + 256*i];
        }
        __syncthreads();
        int cc = cc16*16;
#pragma unroll
        for (int cg = 0; cg < 16; cg += 4) {
            float4 wv4[9];
#pragma unroll
            for (int tap = 0; tap < 9; tap++)
                wv4[tap] = *(const float4*)&wlds[(tap*64 + c)*16 + cg];
            float4 fr4[3][6];
#pragma unroll
            for (int r = 0; r < 3; r++)
#pragma unroll
                for (int cl = 0; cl < 6; cl++)
                    fr4[r][cl] = *(const float4*)&flds[(w + r)*6 + cl][cc + cg];
#pragma unroll
            for (int k = 0; k < 4; k++) {
#pragma unroll
                for (int ky = 0; ky < 3; ky++) {
#pragma unroll
                    for (int kx = 0; kx < 3; kx++) {
                        float wv = ((const float*)&wv4[ky*3 + kx])[k];
                        h0 = fmaf(wv, ((const float*)&fr4[ky][kx + 0])[k], h0);
                        h1 = fmaf(wv, ((const float*)&fr4[ky][kx + 1])[k], h1);
                        h2 = fmaf(wv, ((const float*)&fr4[ky][kx + 2])[k], h2);
                        h3 = fmaf(wv, ((const float*)&fr4[ky][kx + 3])[k], h3);
                    }
                }
            }
        }
    }

    float sc = bns[c], sh = bnsh[c];
    {
        float v0 = fmaf(h0, sc, sh); hl[w*4 + 0][c] = v0 > 0.f ? v0 : 0.f;
        float v1 = fmaf(h1, sc, sh); hl[w*4 + 1][c] = v1 > 0.f ? v1 : 0.f;
        float v2 = fmaf(h2, sc, sh); hl[w*4 + 2][c] = v2 > 0.f ? v2 : 0.f;
        float v3 = fmaf(h3, sc, sh); hl[w*4 + 3][c] = v3 > 0.f ? v3 : 0.f;
    }
    __syncthreads();

    float l0 = b2[c], l1 = l0, l2 = l0, l3 = l0;
    for (int c2 = 0; c2 < C_; c2++) {
        float wv = w2t[c2*D_ + c];
        l0 = fmaf(wv, hl[w*4 + 0][c2], l0);
        l1 = fmaf(wv, hl[w*4 + 1][c2], l1);
        l2 = fmaf(wv, hl[w*4 + 2][c2], l2);
        l3 = fmaf(wv, hl[w*4 + 3][c2], l3);
    }

    float lv[4] = {l0, l1, l2, l3};
#pragma unroll
    for (int p = 0; p < 4; p++) {
        float l = lv[p];
        float m = l;
        for (int off = 32; off; off >>= 1) m = fmaxf(m, __shfl_xor(m, off));
        float e = expf(l - m);
        float s = e;
        for (int off = 32; off; off >>= 1) s += __shfl_xor(s, off);
        probs[((size_t)bn*PIX_ + y*FW_ + x0 + p)*D_ + c] = e / s;
    }
}

// ---------------- geometry: cell for point i (f32 chain, validated r4) ------
__device__ __forceinline__ int compute_cell(int i, const float* __restrict__ kinv,
                                            const float* __restrict__ ext) {
#pragma clang fp contract(off)
    int x  = i % FW_;
    int y  = (i / FW_) % FH_;
    int d  = (i / PIX_) % D_;
    int bn = i / PPBN;

    const float* kv = kinv + bn*9;
    const float* e  = ext  + bn*16;

    float u  = (x == FW_-1) ? 703.0f : (float)((double)x * (703.0/43.0));
    float vv = (float)((double)y * 17.0);
    float dd = (d == D_-1) ? 60.0f  : (float)(1.0 + (double)d * (59.0/63.0));

    float px = u * dd;
    float py = vv * dd;
    float pz = dd;

    float cx = (kv[0]*px + kv[1]*py) + kv[2]*pz;
    float cy = (kv[3]*px + kv[4]*py) + kv[5]*pz;
    float cz = (kv[6]*px + kv[7]*py) + kv[8]*pz;

    float ex = (e[0]*cx + e[1]*cy) + e[2]*cz;
    float ey = (e[4]*cx + e[5]*cy) + e[6]*cz;
    ex = ex + e[3];
    ey = ey + e[7];

    float gx = (ex + 50.0f) / 0.5f;
    float gy = (ey + 50.0f) / 0.5f;
    int ix = (int)floorf(gx);
    int iy = (int)floorf(gy);
    return (ix >= 0 && ix < BEVW && iy >= 0 && iy < BEVH) ? (iy*BEVW + ix) : -1;
}

// ---- wave run-aggregation helpers ----
__device__ __forceinline__ void run_info(int fc, int lane,
                                         bool& isLeader, int& runLen, int& lead) {
    int prev = __shfl_up(fc, 1);
    isLeader = (lane == 0) || (fc != prev);
    unsigned long long mask = __ballot(isLeader);
    unsigned long long hi = (lane == 63) ? 0ull : (mask >> (lane + 1));
    int next = hi ? (lane + 1 + __builtin_ctzll(hi)) : 64;
    runLen = next - lane;
    unsigned long long lo = mask & (~0ull >> (63 - lane));
    lead = 63 - __builtin_clzll(lo);
}

// ---------------- geom + histogram (wave-aggregated, no LDS) ----------------
__global__ __launch_bounds__(256) void geomhist_kernel(
        const float* __restrict__ ext, const float* __restrict__ kinv,
        int* __restrict__ counts) {
    int i = blockIdx.x * 256 + threadIdx.x;
    int lane = threadIdx.x & 63;
    int fc = -1;
    if (i < NPTS) {
        int cell = compute_cell(i, kinv, ext);
        if (cell >= 0) fc = (i / (PPBN * N_)) * NCELL + cell;
    }
    bool isLeader; int runLen, lead;
    run_info(fc, lane, isLeader, runLen, lead);
    if (isLeader && fc >= 0) atomicAdd(&counts[fc], runLen);
}

// ---------------- scanA: block-local scan ----------------
__global__ __launch_bounds__(256) void scanA_kernel(
        int* __restrict__ startp, int* __restrict__ cursor, int* __restrict__ bsum) {
    __shared__ int sdata[256];
    int t = threadIdx.x;
    int i = blockIdx.x * 256 + t;
    int v = (i < NBCELL) ? startp[1 + i] : 0;
    sdata[t] = v;
    __syncthreads();
#pragma unroll
    for (int off = 1; off < 256; off <<= 1) {
        int add = (t >= off) ? sdata[t - off] : 0;
        __syncthreads();
        sdata[t] += add;
        __syncthreads();
    }
    if (i < NBCELL) {
        startp[1 + i] = sdata[t];
        cursor[i]     = sdata[t] - v;
    }
    if (t == 255) bsum[blockIdx.x] = sdata[255];
}

// ---------------- scanC': re-scan bsum in LDS + apply offsets ---------------
__global__ __launch_bounds__(512) void scanC_kernel(
        int* __restrict__ startp, int* __restrict__ cursor,
        const int* __restrict__ bsum) {
    __shared__ int sdata[512];
    int t = threadIdx.x;
    int v = (t < NSCANB) ? bsum[t] : 0;
    sdata[t] = v;
    __syncthreads();
#pragma unroll
    for (int off = 1; off < 512; off <<= 1) {
        int add = (t >= off) ? sdata[t - off] : 0;
        __syncthreads();
        sdata[t] += add;
        __syncthreads();
    }
    int i = blockIdx.x * 512 + t;
    if (i >= NBCELL) return;
    int j = i >> 8;                       // which scanA block
    int off = (j == 0) ? 0 : sdata[j - 1];
    startp[1 + i] += off;
    cursor[i]     += off;
}

// ---------------- geom + scatter packed records (wave-aggregated) -----------
// record: .x = prob bits, .y = pixg | (fc << 14)
__global__ __launch_bounds__(256) void geomscatter_kernel(
        const float* __restrict__ ext, const float* __restrict__ kinv,
        const float* __restrict__ probs,
        int* __restrict__ cursor, int2* __restrict__ plist2) {
    int i = blockIdx.x * 256 + threadIdx.x;
    int lane = threadIdx.x & 63;
    int fc = -1, pixg = 0;
    float pr = 0.f;
    if (i < NPTS) {
        int cell = compute_cell(i, kinv, ext);
        if (cell >= 0) {
            int pix = i % PIX_;
            int d   = (i / PIX_) % D_;
            int bn  = i / PPBN;
            fc   = (bn / N_) * NCELL + cell;
            pixg = bn*PIX_ + pix;
            pr   = probs[(size_t)pixg*D_ + d];
        }
    }
    bool isLeader; int runLen, lead;
    run_info(fc, lane, isLeader, runLen, lead);
    int base = 0;
    if (isLeader && fc >= 0) base = atomicAdd(&cursor[fc], runLen);
    base = __shfl(base, lead);
    if (fc >= 0)
        plist2[base + (lane - lead)] = make_int2(__float_as_int(pr),
                                                 pixg | (fc << 14));
}

// ---------------- gather6: staged records + 8-wide product batches ----------
// wave W owns plist[p0, pe). Lane l stages record p0+l (one coalesced load).
// Points processed in groups of 8: 8 uniform readlanes + 8 INDEPENDENT
// feat-row loads + 8 muls (full MLP), then a VALU-only wave-uniform
// segmented-accumulation walk. Flush: run crossing a wave boundary ->
// atomicAdd; fully-contained run -> plain store (exclusive owner).
__global__ __launch_bounds__(256) void gather6_kernel(
        const float* __restrict__ feat_t, const int* __restrict__ startp,
        const int2* __restrict__ plist2, float* __restrict__ out) {
    int gid  = blockIdx.x * 256 + threadIdx.x;
    int W    = gid >> 6;
    int lane = gid & 63;
    int total = startp[NBCELL];
    int p0 = W * PPW;
    if (p0 >= total) return;
    int pe = min(p0 + PPW, total);
    int nvalid = pe - p0;

    // stage my record (one coalesced 512B load per wave)
    int2 myrec = (p0 + lane < total) ? plist2[p0 + lane] : make_int2(0, -1);

    // neighbor cells (continuation detection)
    int prevfc = -1, nextfc = -1;
    if (p0 > 0)     prevfc = (int)(((unsigned)plist2[p0 - 1].y) >> 14);
    if (pe < total) nextfc = (int)(((unsigned)plist2[pe].y) >> 14);

    float acc = 0.f;
    int curfc = (int)(((unsigned)__builtin_amdgcn_readlane(myrec.y, 0)) >> 14);
    bool pendAtomic = (curfc == prevfc);   // open run continues from prev wave

    for (int k0 = 0; k0 < nvalid; k0 += 8) {
        float p[8];
        int   fcb[8];
#pragma unroll
        for (int j = 0; j < 8; j++) {
            int k = k0 + j;
            int ry = __builtin_amdgcn_readlane(myrec.y, k & 63);
            int rx = __builtin_amdgcn_readlane(myrec.x, k & 63);
            bool v = (k < nvalid);
            fcb[j] = v ? (int)(((unsigned)ry) >> 14) : -1;
            float f = v ? feat_t[(size_t)(ry & 0x3FFF)*C_ + lane] : 0.f;
            p[j] = __int_as_float(v ? rx : 0) * f;
        }
#pragma unroll
        for (int j = 0; j < 8; j++) {
            if (fcb[j] < 0) continue;            // tail padding (wave-uniform)
            if (fcb[j] != curfc) {
                int bb   = curfc >= NCELL;
                int cell = curfc - bb*NCELL;
                float* addr = out + ((size_t)(bb*C_ + lane))*NCELL + cell;
                if (pendAtomic) atomicAdd(addr, acc);
                else            *addr = acc;
                acc = 0.f; curfc = fcb[j]; pendAtomic = false;
            }
            acc += p[j];
        }
    }
    // final flush (may continue into next wave's range)
    {
        bool tailCont = (curfc == nextfc);
        int bb   = curfc >= NCELL;
        int cell = curfc - bb*NCELL;
        float* addr = out + ((size_t)(bb*C_ + lane))*NCELL + cell;
        if (pendAtomic || tailCont) atomicAdd(addr, acc);
        else                        *addr = acc;
    }
}

extern "C" void kernel_launch(void* const* d_in, const int* in_sizes, int n_in,
                              void* d_out, int out_size, void* d_ws, size_t ws_size,
                              hipStream_t stream) {
    const float* feat  = (const float*)d_in[0];
    const float* intr  = (const float*)d_in[1];
    const float* ext   = (const float*)d_in[2];
    const float* w1    = (const float*)d_in[3];
    const float* b1    = (const float*)d_in[4];
    const float* gamma = (const float*)d_in[5];
    const float* beta  = (const float*)d_in[6];
    const float* rmean = (const float*)d_in[7];
    const float* rvar  = (const float*)d_in[8];
    const float* w2    = (const float*)d_in[9];
    const float* b2    = (const float*)d_in[10];
    float* out = (float*)d_out;
    (void)in_sizes; (void)n_in; (void)out_size; (void)ws_size;

    // workspace layout (plist2 first for 8B alignment); total ~9.5 MB
    int2*  plist2 = (int2*)d_ws;                    // NPTS int2 = 4.33 MB
    float* w1t    = (float*)(plist2 + NPTS);        // 36864
    float* w2t    = w1t + C_*C_*9;                  // 4096
    float* bns    = w2t + D_*C_;                    // 64
    float* bnsh   = bns + C_;                       // 64
    float* kinv   = bnsh + C_;                      // 108
    float* probs  = kinv + BN_*9;                   // 540672
    float* feat_t = probs + NPTS;                   // 540672
    int*   startp = (int*)(feat_t + NPTS);          // 80001
    int*   cursor = startp + (NBCELL + 1);          // 80000
    int*   bsum   = cursor + NBCELL;                // 313

    // ---- 7-launch pipeline ----
    setup_kernel<<<NB_SETUP, 256, 0, stream>>>(feat, w1, w2, gamma, beta,
                                               rmean, rvar, intr, out, startp,
                                               w1t, w2t, bns, bnsh, kinv, feat_t);
    enc_kernel<<<528, 256, 0, stream>>>(feat_t, w1t, w2t, bns, bnsh, b1, b2, probs);
    geomhist_kernel<<<NPTS/256, 256, 0, stream>>>(ext, kinv, startp + 1);
    scanA_kernel<<<NSCANB, 256, 0, stream>>>(startp, cursor, bsum);
    scanC_kernel<<<(NBCELL + 511)/512, 512, 0, stream>>>(startp, cursor, bsum);
    geomscatter_kernel<<<NPTS/256, 256, 0, stream>>>(ext, kinv, probs, cursor, plist2);
    gather6_kernel<<<GBLK, 256, 0, stream>>>(feat_t, startp, plist2, out);
}

// Round 18
// 205.523 us; speedup vs baseline: 1.0655x; 1.0655x over previous
//
#include <hip/hip_runtime.h>
#include <math.h>

#define B_   2
#define N_   6
#define C_   64
#define D_   64
#define FH_  16
#define FW_  44
#define BN_  (B_*N_)              // 12
#define PIX_ (FH_*FW_)            // 704
#define NPIX (BN_*PIX_)           // 8448
#define NPTS (BN_*D_*PIX_)        // 540672
#define PPBN (D_*PIX_)            // 45056 points per (b,n) image
#define BEVH 200
#define BEVW 200
#define NCELL (BEVH*BEVW)         // 40000
#define NBCELL (B_*NCELL)         // 80000
#define NSCANB ((NBCELL + 255)/256)  // 313 scan blocks
#define PPW  64                   // points per wave in gather
#define GBLK (NPTS/(PPW*4))       // 2112 gather blocks (4 waves each)
// record pack: pixg (14 bits, max 8447) | fc << 14 (17 bits, max 79999) -> <2^31

// setup mega-kernel block ranges
#define NB_ZOUT 5000              // out zero: 5.12M f32 = 1.28M float4
#define NB_ZSP  313               // startp zero (80001 ints)
#define NB_TW   160               // weight transposes (40960 elems)
#define NB_PREP 1                 // BN affine + Kinv
#define NB_FT   132               // feat transpose
#define NB_SETUP (NB_ZOUT + NB_ZSP + NB_TW + NB_PREP + NB_FT)   // 5606

// ---------------- setup: zero out + zero startp + transW + prep + featT -----
// w1t layout (for b128 enc reads): [cin-chunk(4)][tap(9)][cout(64)][cin%16]
__global__ __launch_bounds__(256) void setup_kernel(
        const float* __restrict__ feat, const float* __restrict__ w1,
        const float* __restrict__ w2,
        const float* __restrict__ gamma, const float* __restrict__ beta,
        const float* __restrict__ rmean, const float* __restrict__ rvar,
        const float* __restrict__ intr,
        float* __restrict__ out, int* __restrict__ startp,
        float* __restrict__ w1t, float* __restrict__ w2t,
        float* __restrict__ bns, float* __restrict__ bnsh,
        float* __restrict__ kinv, float* __restrict__ feat_t) {
#pragma clang fp contract(off)
    __shared__ float lds[64][65];
    int blk = blockIdx.x;
    int t   = threadIdx.x;

    if (blk < NB_ZOUT) {
        ((float4*)out)[blk*256 + t] = float4{0.f, 0.f, 0.f, 0.f};
        return;
    }
    blk -= NB_ZOUT;
    if (blk < NB_ZSP) {
        int i = blk*256 + t;
        if (i < NBCELL + 1) startp[i] = 0;
        return;
    }
    blk -= NB_ZSP;
    if (blk < NB_TW) {
        int idx = blk*256 + t;
        if (idx < C_*C_*9) {
            int cout = idx / (C_*9);
            int r    = idx % (C_*9);
            int cin  = r / 9;
            int tap  = r % 9;
            w1t[(((cin >> 4)*9 + tap)*64 + cout)*16 + (cin & 15)] = w1[idx];
        } else if (idx < C_*C_*9 + D_*C_) {
            int j = idx - C_*C_*9;
            int d = j / C_, c = j % C_;
            w2t[c*D_ + d] = w2[j];
        }
        return;
    }
    blk -= NB_TW;
    if (blk < NB_PREP) {
        if (t < C_) {
            float s = gamma[t] / sqrtf(rvar[t] + 1e-5f);
            bns[t]  = s;
            bnsh[t] = beta[t] - rmean[t] * s;
        }
        if (t < BN_) {
            const float* K = intr + t*9;
            float A[3][3];
            for (int r = 0; r < 3; r++)
                for (int cc = 0; cc < 3; cc++) A[r][cc] = K[r*3 + cc];
            int ipiv[3];
            // sgetf2
            for (int j = 0; j < 3; j++) {
                int p = j; float mx = fabsf(A[j][j]);
                for (int i = j+1; i < 3; i++) {
                    float v = fabsf(A[i][j]);
                    if (v > mx) { mx = v; p = i; }
                }
                ipiv[j] = p;
                if (p != j)
                    for (int k = 0; k < 3; k++) { float tm = A[j][k]; A[j][k] = A[p][k]; A[p][k] = tm; }
                float rpiv = 1.0f / A[j][j];
                for (int i = j+1; i < 3; i++) A[i][j] = A[i][j] * rpiv;
                for (int k = j+1; k < 3; k++)
                    for (int i = j+1; i < 3; i++)
                        A[i][k] = A[i][k] - A[i][j] * A[j][k];
            }
            // strti2
            for (int j = 0; j < 3; j++) {
                float ajj = 1.0f / A[j][j];
                A[j][j] = ajj;
                float najj = -ajj;
                for (int jj = 0; jj < j; jj++) {
                    float temp = A[jj][j];
                    for (int i = 0; i < jj; i++) A[i][j] = A[i][j] + temp * A[i][jj];
                    A[jj][j] = A[jj][j] * A[jj][jj];
                }
                for (int i = 0; i < j; i++) A[i][j] = A[i][j] * najj;
            }
            // sgetri
            for (int j = 1; j >= 0; j--) {
                float work[3];
                for (int i = j+1; i < 3; i++) { work[i] = A[i][j]; A[i][j] = 0.0f; }
                for (int k = j+1; k < 3; k++)
                    for (int i = 0; i < 3; i++)
                        A[i][j] = A[i][j] - A[i][k] * work[k];
            }
            for (int j = 2; j >= 0; j--) {
                int p = ipiv[j];
                if (p != j)
                    for (int i = 0; i < 3; i++) { float tm = A[i][j]; A[i][j] = A[i][p]; A[i][p] = tm; }
            }
            for (int k = 0; k < 9; k++) kinv[t*9 + k] = A[k/3][k%3];
        }
        return;
    }
    blk -= NB_PREP;
    // featT: [bn][c][pix] -> [bn*704+pix][c]
    {
        int bn   = blk / 11;
        int pb   = (blk % 11) * 64;
        int lane = t & 63;
        int r0   = t >> 6;
#pragma unroll
        for (int rr = 0; rr < 16; rr++) {
            int c = r0 + 4*rr;
            lds[c][lane] = feat[((size_t)bn*C_ + c)*PIX_ + pb + lane];
        }
        __syncthreads();
#pragma unroll
        for (int rr = 0; rr < 16; rr++) {
            int pr = r0 + 4*rr;
            feat_t[((size_t)bn*PIX_ + pb + pr)*C_ + lane] = lds[lane][pr];
        }
    }
}

// ---------------- enc v5: b128 LDS reads (4-ci weight/feature vectors) ------
__global__ __launch_bounds__(256) void enc_kernel(
        const float* __restrict__ feat_t,
        const float* __restrict__ w1t, const float* __restrict__ w2t,
        const float* __restrict__ bns, const float* __restrict__ bnsh,
        const float* __restrict__ b1,  const float* __restrict__ b2,
        float* __restrict__ probs) {
    __shared__ float wlds[9*C_*16];    // 36 KB: one 16-ci weight chunk
    __shared__ float flds[36][C_];     // 9 KB: 6x6 pixel window x 64 chan
    __shared__ float hl[16][C_];       // 4 KB
    int blk = blockIdx.x;              // 0..527
    int bn  = blk / 44;
    int rem = blk % 44;
    int yt  = rem / 11;
    int xt  = rem % 11;
    int t   = threadIdx.x;
    int c   = t & 63;
    int w   = __builtin_amdgcn_readfirstlane(t >> 6);   // wave id 0..3
    int y0  = yt*4;
    int x0  = xt*4;
    int y   = y0 + w;

    // stage feature window (zero-padded halo), coalesced from feat_t
    for (int s = w; s < 36; s += 4) {
        int srow = s / 6, scol = s % 6;
        int grow = y0 - 1 + srow;
        int gcol = x0 - 1 + scol;
        float v = 0.f;
        if (grow >= 0 && grow < FH_ && gcol >= 0 && gcol < FW_)
            v = feat_t[((size_t)bn*PIX_ + grow*FW_ + gcol)*C_ + c];
        flds[s][c] = v;
    }

    float h0 = b1[c], h1 = h0, h2 = h0, h3 = h0;

    for (int cc16 = 0; cc16 < 4; cc16++) {
        __syncthreads();               // covers flds (1st iter) + wlds reuse
        {
            const float4* s4 = (const float4*)(w1t + cc16*(9*C_*16));
            float4* d4 = (float4*)wlds;
#pragma unroll
            for (int i = 0; i < 9; i++)
                d4[t + 256*i] = s4[t + 256*i];
        }
        __syncthreads();
        int cc = cc16*16;
#pragma unroll
        for (int cg = 0; cg < 16; cg += 4) {
            float4 wv4[9];
#pragma unroll
            for (int tap = 0; tap < 9; tap++)
                wv4[tap] = *(const float4*)&wlds[(tap*64 + c)*16 + cg];
            float4 fr4[3][6];
#pragma unroll
            for (int r = 0; r < 3; r++)
#pragma unroll
                for (int cl = 0; cl < 6; cl++)
                    fr4[r][cl] = *(const float4*)&flds[(w + r)*6 + cl][cc + cg];
#pragma unroll
            for (int k = 0; k < 4; k++) {
#pragma unroll
                for (int ky = 0; ky < 3; ky++) {
#pragma unroll
                    for (int kx = 0; kx < 3; kx++) {
                        float wv = ((const float*)&wv4[ky*3 + kx])[k];
                        h0 = fmaf(wv, ((const float*)&fr4[ky][kx + 0])[k], h0);
                        h1 = fmaf(wv, ((const float*)&fr4[ky][kx + 1])[k], h1);
                        h2 = fmaf(wv, ((const float*)&fr4[ky][kx + 2])[k], h2);
                        h3 = fmaf(wv, ((const float*)&fr4[ky][kx + 3])[k], h3);
                    }
                }
            }
        }
    }

    float sc = bns[c], sh = bnsh[c];
    {
        float v0 = fmaf(h0, sc, sh); hl[w*4 + 0][c] = v0 > 0.f ? v0 : 0.f;
        float v1 = fmaf(h1, sc, sh); hl[w*4 + 1][c] = v1 > 0.f ? v1 : 0.f;
        float v2 = fmaf(h2, sc, sh); hl[w*4 + 2][c] = v2 > 0.f ? v2 : 0.f;
        float v3 = fmaf(h3, sc, sh); hl[w*4 + 3][c] = v3 > 0.f ? v3 : 0.f;
    }
    __syncthreads();

    float l0 = b2[c], l1 = l0, l2 = l0, l3 = l0;
    for (int c2 = 0; c2 < C_; c2++) {
        float wv = w2t[c2*D_ + c];
        l0 = fmaf(wv, hl[w*4 + 0][c2], l0);
        l1 = fmaf(wv, hl[w*4 + 1][c2], l1);
        l2 = fmaf(wv, hl[w*4 + 2][c2], l2);
        l3 = fmaf(wv, hl[w*4 + 3][c2], l3);
    }

    float lv[4] = {l0, l1, l2, l3};
#pragma unroll
    for (int p = 0; p < 4; p++) {
        float l = lv[p];
        float m = l;
        for (int off = 32; off; off >>= 1) m = fmaxf(m, __shfl_xor(m, off));
        float e = expf(l - m);
        float s = e;
        for (int off = 32; off; off >>= 1) s += __shfl_xor(s, off);
        probs[((size_t)bn*PIX_ + y*FW_ + x0 + p)*D_ + c] = e / s;
    }
}

// ---------------- geometry: cell for point i (f32 chain, validated r4) ------
__device__ __forceinline__ int compute_cell(int i, const float* __restrict__ kinv,
                                            const float* __restrict__ ext) {
#pragma clang fp contract(off)
    int x  = i % FW_;
    int y  = (i / FW_) % FH_;
    int d  = (i / PIX_) % D_;
    int bn = i / PPBN;

    const float* kv = kinv + bn*9;
    const float* e  = ext  + bn*16;

    float u  = (x == FW_-1) ? 703.0f : (float)((double)x * (703.0/43.0));
    float vv = (float)((double)y * 17.0);
    float dd = (d == D_-1) ? 60.0f  : (float)(1.0 + (double)d * (59.0/63.0));

    float px = u * dd;
    float py = vv * dd;
    float pz = dd;

    float cx = (kv[0]*px + kv[1]*py) + kv[2]*pz;
    float cy = (kv[3]*px + kv[4]*py) + kv[5]*pz;
    float cz = (kv[6]*px + kv[7]*py) + kv[8]*pz;

    float ex = (e[0]*cx + e[1]*cy) + e[2]*cz;
    float ey = (e[4]*cx + e[5]*cy) + e[6]*cz;
    ex = ex + e[3];
    ey = ey + e[7];

    float gx = (ex + 50.0f) / 0.5f;
    float gy = (ey + 50.0f) / 0.5f;
    int ix = (int)floorf(gx);
    int iy = (int)floorf(gy);
    return (ix >= 0 && ix < BEVW && iy >= 0 && iy < BEVH) ? (iy*BEVW + ix) : -1;
}

// ---- wave run-aggregation helpers ----
__device__ __forceinline__ void run_info(int fc, int lane,
                                         bool& isLeader, int& runLen, int& lead) {
    int prev = __shfl_up(fc, 1);
    isLeader = (lane == 0) || (fc != prev);
    unsigned long long mask = __ballot(isLeader);
    unsigned long long hi = (lane == 63) ? 0ull : (mask >> (lane + 1));
    int next = hi ? (lane + 1 + __builtin_ctzll(hi)) : 64;
    runLen = next - lane;
    unsigned long long lo = mask & (~0ull >> (63 - lane));
    lead = 63 - __builtin_clzll(lo);
}

// ---------------- geom + histogram (wave-aggregated, no LDS) ----------------
__global__ __launch_bounds__(256) void geomhist_kernel(
        const float* __restrict__ ext, const float* __restrict__ kinv,
        int* __restrict__ counts) {
    int i = blockIdx.x * 256 + threadIdx.x;
    int lane = threadIdx.x & 63;
    int fc = -1;
    if (i < NPTS) {
        int cell = compute_cell(i, kinv, ext);
        if (cell >= 0) fc = (i / (PPBN * N_)) * NCELL + cell;
    }
    bool isLeader; int runLen, lead;
    run_info(fc, lane, isLeader, runLen, lead);
    if (isLeader && fc >= 0) atomicAdd(&counts[fc], runLen);
}

// ---------------- scanA: block-local scan ----------------
__global__ __launch_bounds__(256) void scanA_kernel(
        int* __restrict__ startp, int* __restrict__ cursor, int* __restrict__ bsum) {
    __shared__ int sdata[256];
    int t = threadIdx.x;
    int i = blockIdx.x * 256 + t;
    int v = (i < NBCELL) ? startp[1 + i] : 0;
    sdata[t] = v;
    __syncthreads();
#pragma unroll
    for (int off = 1; off < 256; off <<= 1) {
        int add = (t >= off) ? sdata[t - off] : 0;
        __syncthreads();
        sdata[t] += add;
        __syncthreads();
    }
    if (i < NBCELL) {
        startp[1 + i] = sdata[t];
        cursor[i]     = sdata[t] - v;
    }
    if (t == 255) bsum[blockIdx.x] = sdata[255];
}

// ---------------- scanC': re-scan bsum in LDS + apply offsets ---------------
__global__ __launch_bounds__(512) void scanC_kernel(
        int* __restrict__ startp, int* __restrict__ cursor,
        const int* __restrict__ bsum) {
    __shared__ int sdata[512];
    int t = threadIdx.x;
    int v = (t < NSCANB) ? bsum[t] : 0;
    sdata[t] = v;
    __syncthreads();
#pragma unroll
    for (int off = 1; off < 512; off <<= 1) {
        int add = (t >= off) ? sdata[t - off] : 0;
        __syncthreads();
        sdata[t] += add;
        __syncthreads();
    }
    int i = blockIdx.x * 512 + t;
    if (i >= NBCELL) return;
    int j = i >> 8;                       // which scanA block
    int off = (j == 0) ? 0 : sdata[j - 1];
    startp[1 + i] += off;
    cursor[i]     += off;
}

// ---------------- geom + scatter packed records (wave-aggregated) -----------
// record: .x = prob bits, .y = pixg | (fc << 14)
__global__ __launch_bounds__(256) void geomscatter_kernel(
        const float* __restrict__ ext, const float* __restrict__ kinv,
        const float* __restrict__ probs,
        int* __restrict__ cursor, int2* __restrict__ plist2) {
    int i = blockIdx.x * 256 + threadIdx.x;
    int lane = threadIdx.x & 63;
    int fc = -1, pixg = 0;
    float pr = 0.f;
    if (i < NPTS) {
        int cell = compute_cell(i, kinv, ext);
        if (cell >= 0) {
            int pix = i % PIX_;
            int d   = (i / PIX_) % D_;
            int bn  = i / PPBN;
            fc   = (bn / N_) * NCELL + cell;
            pixg = bn*PIX_ + pix;
            pr   = probs[(size_t)pixg*D_ + d];
        }
    }
    bool isLeader; int runLen, lead;
    run_info(fc, lane, isLeader, runLen, lead);
    int base = 0;
    if (isLeader && fc >= 0) base = atomicAdd(&cursor[fc], runLen);
    base = __shfl(base, lead);
    if (fc >= 0)
        plist2[base + (lane - lead)] = make_int2(__float_as_int(pr),
                                                 pixg | (fc << 14));
}

// ---- 4-way ILP cell accumulation: 4 independent FMA chains, loads batched --
__device__ __forceinline__ float cell_accum(
        const int2* __restrict__ plist2, const float* __restrict__ feat_t,
        int q0, int q1, int lane) {
    float a0 = 0.f, a1 = 0.f, a2 = 0.f, a3 = 0.f;
    int q = q0;
    for (; q + 4 <= q1; q += 4) {
        int2 r0 = plist2[q];
        int2 r1 = plist2[q + 1];
        int2 r2 = plist2[q + 2];
        int2 r3 = plist2[q + 3];
        float f0 = feat_t[(size_t)(r0.y & 0x3FFF)*C_ + lane];
        float f1 = feat_t[(size_t)(r1.y & 0x3FFF)*C_ + lane];
        float f2 = feat_t[(size_t)(r2.y & 0x3FFF)*C_ + lane];
        float f3 = feat_t[(size_t)(r3.y & 0x3FFF)*C_ + lane];
        a0 = fmaf(__int_as_float(r0.x), f0, a0);
        a1 = fmaf(__int_as_float(r1.x), f1, a1);
        a2 = fmaf(__int_as_float(r2.x), f2, a2);
        a3 = fmaf(__int_as_float(r3.x), f3, a3);
    }
    for (; q < q1; q++) {
        int2 r = plist2[q];
        a0 = fmaf(__int_as_float(r.x),
                  feat_t[(size_t)(r.y & 0x3FFF)*C_ + lane], a0);
    }
    return (a0 + a1) + (a2 + a3);
}

// ---------------- gather4: point-balanced + 4-way ILP (r14, proven 69us) ----
// wave W covers plist[W*PPW, (W+1)*PPW) snapped to cell boundaries.
// small cell (len<=2*PPW): owned by the wave containing its START -> store.
// big cell: each overlapping wave adds its slice via atomicAdd.
__global__ __launch_bounds__(256) void gather4_kernel(
        const float* __restrict__ feat_t, const int* __restrict__ startp,
        const int2* __restrict__ plist2, float* __restrict__ out) {
    int gid  = blockIdx.x * 256 + threadIdx.x;
    int W    = gid >> 6;
    int lane = gid & 63;
    int total = startp[NBCELL];
    int p0 = W * PPW;
    if (p0 >= total) return;
    int pe = min(p0 + PPW, total);
    int p  = p0;

    // head: cell continuing from a previous wave's range
    {
        int2 r = plist2[p0];
        int fc = ((unsigned)r.y) >> 14;
        int cs = startp[fc], ce = startp[fc + 1];
        if (cs < p0) {
            if (ce - cs > 2*PPW) {        // big: process our slice
                float acc = cell_accum(plist2, feat_t, p0, min(pe, ce), lane);
                int bb   = fc >= NCELL;
                int cell = fc - bb*NCELL;
                atomicAdd(out + ((size_t)(bb*C_ + lane))*NCELL + cell, acc);
            }
            p = ce;                        // small: skip (owned upstream)
        }
    }
    // cells starting in [p, pe)
    while (p < pe) {
        int2 r = plist2[p];
        int fc = ((unsigned)r.y) >> 14;
        int ce = startp[fc + 1];
        bool big = (ce - p > 2*PPW);
        int b2 = big ? min(ce, pe) : ce;   // small may extend past pe (owned)
        float acc = cell_accum(plist2, feat_t, p, b2, lane);
        int bb   = fc >= NCELL;
        int cell = fc - bb*NCELL;
        float* addr = out + ((size_t)(bb*C_ + lane))*NCELL + cell;
        if (big) atomicAdd(addr, acc);
        else     *addr = acc;
        p = ce;
    }
}

extern "C" void kernel_launch(void* const* d_in, const int* in_sizes, int n_in,
                              void* d_out, int out_size, void* d_ws, size_t ws_size,
                              hipStream_t stream) {
    const float* feat  = (const float*)d_in[0];
    const float* intr  = (const float*)d_in[1];
    const float* ext   = (const float*)d_in[2];
    const float* w1    = (const float*)d_in[3];
    const float* b1    = (const float*)d_in[4];
    const float* gamma = (const float*)d_in[5];
    const float* beta  = (const float*)d_in[6];
    const float* rmean = (const float*)d_in[7];
    const float* rvar  = (const float*)d_in[8];
    const float* w2    = (const float*)d_in[9];
    const float* b2    = (const float*)d_in[10];
    float* out = (float*)d_out;
    (void)in_sizes; (void)n_in; (void)out_size; (void)ws_size;

    // workspace layout (plist2 first for 8B alignment); total ~9.5 MB
    int2*  plist2 = (int2*)d_ws;                    // NPTS int2 = 4.33 MB
    float* w1t    = (float*)(plist2 + NPTS);        // 36864
    float* w2t    = w1t + C_*C_*9;                  // 4096
    float* bns    = w2t + D_*C_;                    // 64
    float* bnsh   = bns + C_;                       // 64
    float* kinv   = bnsh + C_;                      // 108
    float* probs  = kinv + BN_*9;                   // 540672
    float* feat_t = probs + NPTS;                   // 540672
    int*   startp = (int*)(feat_t + NPTS);          // 80001
    int*   cursor = startp + (NBCELL + 1);          // 80000
    int*   bsum   = cursor + NBCELL;                // 313

    // ---- 7-launch pipeline ----
    setup_kernel<<<NB_SETUP, 256, 0, stream>>>(feat, w1, w2, gamma, beta,
                                               rmean, rvar, intr, out, startp,
                                               w1t, w2t, bns, bnsh, kinv, feat_t);
    enc_kernel<<<528, 256, 0, stream>>>(feat_t, w1t, w2t, bns, bnsh, b1, b2, probs);
    geomhist_kernel<<<NPTS/256, 256, 0, stream>>>(ext, kinv, startp + 1);
    scanA_kernel<<<NSCANB, 256, 0, stream>>>(startp, cursor, bsum);
    scanC_kernel<<<(NBCELL + 511)/512, 512, 0, stream>>>(startp, cursor, bsum);
    geomscatter_kernel<<<NPTS/256, 256, 0, stream>>>(ext, kinv, probs, cursor, plist2);
    gather4_kernel<<<GBLK, 256, 0, stream>>>(feat_t, startp, plist2, out);
}

// Round 19
// 188.585 us; speedup vs baseline: 1.1612x; 1.0898x over previous
//
#include <hip/hip_runtime.h>
#include <math.h>

#define B_   2
#define N_   6
#define C_   64
#define D_   64
#define FH_  16
#define FW_  44
#define BN_  (B_*N_)              // 12
#define PIX_ (FH_*FW_)            // 704
#define NPIX (BN_*PIX_)           // 8448
#define NPTS (BN_*D_*PIX_)        // 540672
#define PPBN (D_*PIX_)            // 45056 points per (b,n) image
#define BEVH 200
#define BEVW 200
#define NCELL (BEVH*BEVW)         // 40000
#define NBCELL (B_*NCELL)         // 80000
#define NSCANB ((NBCELL + 255)/256)  // 313 scan blocks
#define PPW  64                   // points per wave in gather
#define GBLK (NPTS/(PPW*4))       // 2112 gather blocks (4 waves each)
#define NXCD 8
#define GCHUNK (GBLK/NXCD)        // 264 (2112 % 8 == 0 -> bijective swizzle)
#define SCBLK (NPTS/256)          // 2112 scatter blocks (same swizzle)
// record pack: pixg (14 bits, max 8447) | fc << 14 (17 bits, max 79999) -> <2^31

// setup mega-kernel block ranges
#define NB_ZOUT 5000              // out zero: 5.12M f32 = 1.28M float4
#define NB_ZSP  313               // startp zero (80001 ints)
#define NB_TW   160               // weight transposes (40960 elems)
#define NB_PREP 1                 // BN affine + Kinv
#define NB_FT   132               // feat transpose
#define NB_SETUP (NB_ZOUT + NB_ZSP + NB_TW + NB_PREP + NB_FT)   // 5606

// ---------------- setup: zero out + zero startp + transW + prep + featT -----
// w1t layout (for b128 enc reads): [cin-chunk(4)][tap(9)][cout(64)][cin%16]
__global__ __launch_bounds__(256) void setup_kernel(
        const float* __restrict__ feat, const float* __restrict__ w1,
        const float* __restrict__ w2,
        const float* __restrict__ gamma, const float* __restrict__ beta,
        const float* __restrict__ rmean, const float* __restrict__ rvar,
        const float* __restrict__ intr,
        float* __restrict__ out, int* __restrict__ startp,
        float* __restrict__ w1t, float* __restrict__ w2t,
        float* __restrict__ bns, float* __restrict__ bnsh,
        float* __restrict__ kinv, float* __restrict__ feat_t) {
#pragma clang fp contract(off)
    __shared__ float lds[64][65];
    int blk = blockIdx.x;
    int t   = threadIdx.x;

    if (blk < NB_ZOUT) {
        ((float4*)out)[blk*256 + t] = float4{0.f, 0.f, 0.f, 0.f};
        return;
    }
    blk -= NB_ZOUT;
    if (blk < NB_ZSP) {
        int i = blk*256 + t;
        if (i < NBCELL + 1) startp[i] = 0;
        return;
    }
    blk -= NB_ZSP;
    if (blk < NB_TW) {
        int idx = blk*256 + t;
        if (idx < C_*C_*9) {
            int cout = idx / (C_*9);
            int r    = idx % (C_*9);
            int cin  = r / 9;
            int tap  = r % 9;
            w1t[(((cin >> 4)*9 + tap)*64 + cout)*16 + (cin & 15)] = w1[idx];
        } else if (idx < C_*C_*9 + D_*C_) {
            int j = idx - C_*C_*9;
            int d = j / C_, c = j % C_;
            w2t[c*D_ + d] = w2[j];
        }
        return;
    }
    blk -= NB_TW;
    if (blk < NB_PREP) {
        if (t < C_) {
            float s = gamma[t] / sqrtf(rvar[t] + 1e-5f);
            bns[t]  = s;
            bnsh[t] = beta[t] - rmean[t] * s;
        }
        if (t < BN_) {
            const float* K = intr + t*9;
            float A[3][3];
            for (int r = 0; r < 3; r++)
                for (int cc = 0; cc < 3; cc++) A[r][cc] = K[r*3 + cc];
            int ipiv[3];
            // sgetf2
            for (int j = 0; j < 3; j++) {
                int p = j; float mx = fabsf(A[j][j]);
                for (int i = j+1; i < 3; i++) {
                    float v = fabsf(A[i][j]);
                    if (v > mx) { mx = v; p = i; }
                }
                ipiv[j] = p;
                if (p != j)
                    for (int k = 0; k < 3; k++) { float tm = A[j][k]; A[j][k] = A[p][k]; A[p][k] = tm; }
                float rpiv = 1.0f / A[j][j];
                for (int i = j+1; i < 3; i++) A[i][j] = A[i][j] * rpiv;
                for (int k = j+1; k < 3; k++)
                    for (int i = j+1; i < 3; i++)
                        A[i][k] = A[i][k] - A[i][j] * A[j][k];
            }
            // strti2
            for (int j = 0; j < 3; j++) {
                float ajj = 1.0f / A[j][j];
                A[j][j] = ajj;
                float najj = -ajj;
                for (int jj = 0; jj < j; jj++) {
                    float temp = A[jj][j];
                    for (int i = 0; i < jj; i++) A[i][j] = A[i][j] + temp * A[i][jj];
                    A[jj][j] = A[jj][j] * A[jj][jj];
                }
                for (int i = 0; i < j; i++) A[i][j] = A[i][j] * najj;
            }
            // sgetri
            for (int j = 1; j >= 0; j--) {
                float work[3];
                for (int i = j+1; i < 3; i++) { work[i] = A[i][j]; A[i][j] = 0.0f; }
                for (int k = j+1; k < 3; k++)
                    for (int i = 0; i < 3; i++)
                        A[i][j] = A[i][j] - A[i][k] * work[k];
            }
            for (int j = 2; j >= 0; j--) {
                int p = ipiv[j];
                if (p != j)
                    for (int i = 0; i < 3; i++) { float tm = A[i][j]; A[i][j] = A[i][p]; A[i][p] = tm; }
            }
            for (int k = 0; k < 9; k++) kinv[t*9 + k] = A[k/3][k%3];
        }
        return;
    }
    blk -= NB_PREP;
    // featT: [bn][c][pix] -> [bn*704+pix][c]
    {
        int bn   = blk / 11;
        int pb   = (blk % 11) * 64;
        int lane = t & 63;
        int r0   = t >> 6;
#pragma unroll
        for (int rr = 0; rr < 16; rr++) {
            int c = r0 + 4*rr;
            lds[c][lane] = feat[((size_t)bn*C_ + c)*PIX_ + pb + lane];
        }
        __syncthreads();
#pragma unroll
        for (int rr = 0; rr < 16; rr++) {
            int pr = r0 + 4*rr;
            feat_t[((size_t)bn*PIX_ + pb + pr)*C_ + lane] = lds[lane][pr];
        }
    }
}

// ---------------- enc v5: b128 LDS reads (4-ci weight/feature vectors) ------
__global__ __launch_bounds__(256) void enc_kernel(
        const float* __restrict__ feat_t,
        const float* __restrict__ w1t, const float* __restrict__ w2t,
        const float* __restrict__ bns, const float* __restrict__ bnsh,
        const float* __restrict__ b1,  const float* __restrict__ b2,
        float* __restrict__ probs) {
    __shared__ float wlds[9*C_*16];    // 36 KB: one 16-ci weight chunk
    __shared__ float flds[36][C_];     // 9 KB: 6x6 pixel window x 64 chan
    __shared__ float hl[16][C_];       // 4 KB
    int blk = blockIdx.x;              // 0..527
    int bn  = blk / 44;
    int rem = blk % 44;
    int yt  = rem / 11;
    int xt  = rem % 11;
    int t   = threadIdx.x;
    int c   = t & 63;
    int w   = __builtin_amdgcn_readfirstlane(t >> 6);   // wave id 0..3
    int y0  = yt*4;
    int x0  = xt*4;
    int y   = y0 + w;

    // stage feature window (zero-padded halo), coalesced from feat_t
    for (int s = w; s < 36; s += 4) {
        int srow = s / 6, scol = s % 6;
        int grow = y0 - 1 + srow;
        int gcol = x0 - 1 + scol;
        float v = 0.f;
        if (grow >= 0 && grow < FH_ && gcol >= 0 && gcol < FW_)
            v = feat_t[((size_t)bn*PIX_ + grow*FW_ + gcol)*C_ + c];
        flds[s][c] = v;
    }

    float h0 = b1[c], h1 = h0, h2 = h0, h3 = h0;

    for (int cc16 = 0; cc16 < 4; cc16++) {
        __syncthreads();               // covers flds (1st iter) + wlds reuse
        {
            const float4* s4 = (const float4*)(w1t + cc16*(9*C_*16));
            float4* d4 = (float4*)wlds;
#pragma unroll
            for (int i = 0; i < 9; i++)
                d4[t + 256*i] = s4[t + 256*i];
        }
        __syncthreads();
        int cc = cc16*16;
#pragma unroll
        for (int cg = 0; cg < 16; cg += 4) {
            float4 wv4[9];
#pragma unroll
            for (int tap = 0; tap < 9; tap++)
                wv4[tap] = *(const float4*)&wlds[(tap*64 + c)*16 + cg];
            float4 fr4[3][6];
#pragma unroll
            for (int r = 0; r < 3; r++)
#pragma unroll
                for (int cl = 0; cl < 6; cl++)
                    fr4[r][cl] = *(const float4*)&flds[(w + r)*6 + cl][cc + cg];
#pragma unroll
            for (int k = 0; k < 4; k++) {
#pragma unroll
                for (int ky = 0; ky < 3; ky++) {
#pragma unroll
                    for (int kx = 0; kx < 3; kx++) {
                        float wv = ((const float*)&wv4[ky*3 + kx])[k];
                        h0 = fmaf(wv, ((const float*)&fr4[ky][kx + 0])[k], h0);
                        h1 = fmaf(wv, ((const float*)&fr4[ky][kx + 1])[k], h1);
                        h2 = fmaf(wv, ((const float*)&fr4[ky][kx + 2])[k], h2);
                        h3 = fmaf(wv, ((const float*)&fr4[ky][kx + 3])[k], h3);
                    }
                }
            }
        }
    }

    float sc = bns[c], sh = bnsh[c];
    {
        float v0 = fmaf(h0, sc, sh); hl[w*4 + 0][c] = v0 > 0.f ? v0 : 0.f;
        float v1 = fmaf(h1, sc, sh); hl[w*4 + 1][c] = v1 > 0.f ? v1 : 0.f;
        float v2 = fmaf(h2, sc, sh); hl[w*4 + 2][c] = v2 > 0.f ? v2 : 0.f;
        float v3 = fmaf(h3, sc, sh); hl[w*4 + 3][c] = v3 > 0.f ? v3 : 0.f;
    }
    __syncthreads();

    float l0 = b2[c], l1 = l0, l2 = l0, l3 = l0;
    for (int c2 = 0; c2 < C_; c2++) {
        float wv = w2t[c2*D_ + c];
        l0 = fmaf(wv, hl[w*4 + 0][c2], l0);
        l1 = fmaf(wv, hl[w*4 + 1][c2], l1);
        l2 = fmaf(wv, hl[w*4 + 2][c2], l2);
        l3 = fmaf(wv, hl[w*4 + 3][c2], l3);
    }

    float lv[4] = {l0, l1, l2, l3};
#pragma unroll
    for (int p = 0; p < 4; p++) {
        float l = lv[p];
        float m = l;
        for (int off = 32; off; off >>= 1) m = fmaxf(m, __shfl_xor(m, off));
        float e = expf(l - m);
        float s = e;
        for (int off = 32; off; off >>= 1) s += __shfl_xor(s, off);
        probs[((size_t)bn*PIX_ + y*FW_ + x0 + p)*D_ + c] = e / s;
    }
}

// ---------------- geometry: cell for point i (f32 chain, validated r4) ------
__device__ __forceinline__ int compute_cell(int i, const float* __restrict__ kinv,
                                            const float* __restrict__ ext) {
#pragma clang fp contract(off)
    int x  = i % FW_;
    int y  = (i / FW_) % FH_;
    int d  = (i / PIX_) % D_;
    int bn = i / PPBN;

    const float* kv = kinv + bn*9;
    const float* e  = ext  + bn*16;

    float u  = (x == FW_-1) ? 703.0f : (float)((double)x * (703.0/43.0));
    float vv = (float)((double)y * 17.0);
    float dd = (d == D_-1) ? 60.0f  : (float)(1.0 + (double)d * (59.0/63.0));

    float px = u * dd;
    float py = vv * dd;
    float pz = dd;

    float cx = (kv[0]*px + kv[1]*py) + kv[2]*pz;
    float cy = (kv[3]*px + kv[4]*py) + kv[5]*pz;
    float cz = (kv[6]*px + kv[7]*py) + kv[8]*pz;

    float ex = (e[0]*cx + e[1]*cy) + e[2]*cz;
    float ey = (e[4]*cx + e[5]*cy) + e[6]*cz;
    ex = ex + e[3];
    ey = ey + e[7];

    float gx = (ex + 50.0f) / 0.5f;
    float gy = (ey + 50.0f) / 0.5f;
    int ix = (int)floorf(gx);
    int iy = (int)floorf(gy);
    return (ix >= 0 && ix < BEVW && iy >= 0 && iy < BEVH) ? (iy*BEVW + ix) : -1;
}

// ---- wave run-aggregation helpers ----
__device__ __forceinline__ void run_info(int fc, int lane,
                                         bool& isLeader, int& runLen, int& lead) {
    int prev = __shfl_up(fc, 1);
    isLeader = (lane == 0) || (fc != prev);
    unsigned long long mask = __ballot(isLeader);
    unsigned long long hi = (lane == 63) ? 0ull : (mask >> (lane + 1));
    int next = hi ? (lane + 1 + __builtin_ctzll(hi)) : 64;
    runLen = next - lane;
    unsigned long long lo = mask & (~0ull >> (63 - lane));
    lead = 63 - __builtin_clzll(lo);
}

// ---------------- geom + histogram (wave-aggregated, no LDS) ----------------
__global__ __launch_bounds__(256) void geomhist_kernel(
        const float* __restrict__ ext, const float* __restrict__ kinv,
        int* __restrict__ counts) {
    int i = blockIdx.x * 256 + threadIdx.x;
    int lane = threadIdx.x & 63;
    int fc = -1;
    if (i < NPTS) {
        int cell = compute_cell(i, kinv, ext);
        if (cell >= 0) fc = (i / (PPBN * N_)) * NCELL + cell;
    }
    bool isLeader; int runLen, lead;
    run_info(fc, lane, isLeader, runLen, lead);
    if (isLeader && fc >= 0) atomicAdd(&counts[fc], runLen);
}

// ---------------- scanA: block-local scan ----------------
__global__ __launch_bounds__(256) void scanA_kernel(
        int* __restrict__ startp, int* __restrict__ cursor, int* __restrict__ bsum) {
    __shared__ int sdata[256];
    int t = threadIdx.x;
    int i = blockIdx.x * 256 + t;
    int v = (i < NBCELL) ? startp[1 + i] : 0;
    sdata[t] = v;
    __syncthreads();
#pragma unroll
    for (int off = 1; off < 256; off <<= 1) {
        int add = (t >= off) ? sdata[t - off] : 0;
        __syncthreads();
        sdata[t] += add;
        __syncthreads();
    }
    if (i < NBCELL) {
        startp[1 + i] = sdata[t];
        cursor[i]     = sdata[t] - v;
    }
    if (t == 255) bsum[blockIdx.x] = sdata[255];
}

// ---------------- scanC': re-scan bsum in LDS + apply offsets ---------------
__global__ __launch_bounds__(512) void scanC_kernel(
        int* __restrict__ startp, int* __restrict__ cursor,
        const int* __restrict__ bsum) {
    __shared__ int sdata[512];
    int t = threadIdx.x;
    int v = (t < NSCANB) ? bsum[t] : 0;
    sdata[t] = v;
    __syncthreads();
#pragma unroll
    for (int off = 1; off < 512; off <<= 1) {
        int add = (t >= off) ? sdata[t - off] : 0;
        __syncthreads();
        sdata[t] += add;
        __syncthreads();
    }
    int i = blockIdx.x * 512 + t;
    if (i >= NBCELL) return;
    int j = i >> 8;                       // which scanA block
    int off = (j == 0) ? 0 : sdata[j - 1];
    startp[1 + i] += off;
    cursor[i]     += off;
}

// ---------------- geom + scatter packed records (wave-aggregated, XCD-swz) --
// record: .x = prob bits, .y = pixg | (fc << 14)
__global__ __launch_bounds__(256) void geomscatter_kernel(
        const float* __restrict__ ext, const float* __restrict__ kinv,
        const float* __restrict__ probs,
        int* __restrict__ cursor, int2* __restrict__ plist2) {
    int blk = (blockIdx.x % NXCD) * (SCBLK/NXCD) + blockIdx.x / NXCD;
    int i = blk * 256 + threadIdx.x;
    int lane = threadIdx.x & 63;
    int fc = -1, pixg = 0;
    float pr = 0.f;
    if (i < NPTS) {
        int cell = compute_cell(i, kinv, ext);
        if (cell >= 0) {
            int pix = i % PIX_;
            int d   = (i / PIX_) % D_;
            int bn  = i / PPBN;
            fc   = (bn / N_) * NCELL + cell;
            pixg = bn*PIX_ + pix;
            pr   = probs[(size_t)pixg*D_ + d];
        }
    }
    bool isLeader; int runLen, lead;
    run_info(fc, lane, isLeader, runLen, lead);
    int base = 0;
    if (isLeader && fc >= 0) base = atomicAdd(&cursor[fc], runLen);
    base = __shfl(base, lead);
    if (fc >= 0)
        plist2[base + (lane - lead)] = make_int2(__float_as_int(pr),
                                                 pixg | (fc << 14));
}

// ---- 4-way ILP cell accumulation: 4 independent FMA chains, loads batched --
__device__ __forceinline__ float cell_accum(
        const int2* __restrict__ plist2, const float* __restrict__ feat_t,
        int q0, int q1, int lane) {
    float a0 = 0.f, a1 = 0.f, a2 = 0.f, a3 = 0.f;
    int q = q0;
    for (; q + 4 <= q1; q += 4) {
        int2 r0 = plist2[q];
        int2 r1 = plist2[q + 1];
        int2 r2 = plist2[q + 2];
        int2 r3 = plist2[q + 3];
        float f0 = feat_t[(size_t)(r0.y & 0x3FFF)*C_ + lane];
        float f1 = feat_t[(size_t)(r1.y & 0x3FFF)*C_ + lane];
        float f2 = feat_t[(size_t)(r2.y & 0x3FFF)*C_ + lane];
        float f3 = feat_t[(size_t)(r3.y & 0x3FFF)*C_ + lane];
        a0 = fmaf(__int_as_float(r0.x), f0, a0);
        a1 = fmaf(__int_as_float(r1.x), f1, a1);
        a2 = fmaf(__int_as_float(r2.x), f2, a2);
        a3 = fmaf(__int_as_float(r3.x), f3, a3);
    }
    for (; q < q1; q++) {
        int2 r = plist2[q];
        a0 = fmaf(__int_as_float(r.x),
                  feat_t[(size_t)(r.y & 0x3FFF)*C_ + lane], a0);
    }
    return (a0 + a1) + (a2 + a3);
}

// ---------------- gather4 + XCD swizzle: contiguous cell chunks per XCD -----
// Block swizzle keeps consecutive plist ranges (= consecutive output cells)
// on ONE XCD so partial 64B output lines coalesce in that XCD's L2 instead
// of bouncing to HBM from 8 non-coherent L2s.
__global__ __launch_bounds__(256) void gather4_kernel(
        const float* __restrict__ feat_t, const int* __restrict__ startp,
        const int2* __restrict__ plist2, float* __restrict__ out) {
    int blk  = (blockIdx.x % NXCD) * GCHUNK + blockIdx.x / NXCD;
    int gid  = blk * 256 + threadIdx.x;
    int W    = gid >> 6;
    int lane = gid & 63;
    int total = startp[NBCELL];
    int p0 = W * PPW;
    if (p0 >= total) return;
    int pe = min(p0 + PPW, total);
    int p  = p0;

    // head: cell continuing from a previous wave's range
    {
        int2 r = plist2[p0];
        int fc = ((unsigned)r.y) >> 14;
        int cs = startp[fc], ce = startp[fc + 1];
        if (cs < p0) {
            if (ce - cs > 2*PPW) {        // big: process our slice
                float acc = cell_accum(plist2, feat_t, p0, min(pe, ce), lane);
                int bb   = fc >= NCELL;
                int cell = fc - bb*NCELL;
                atomicAdd(out + ((size_t)(bb*C_ + lane))*NCELL + cell, acc);
            }
            p = ce;                        // small: skip (owned upstream)
        }
    }
    // cells starting in [p, pe)
    while (p < pe) {
        int2 r = plist2[p];
        int fc = ((unsigned)r.y) >> 14;
        int ce = startp[fc + 1];
        bool big = (ce - p > 2*PPW);
        int b2 = big ? min(ce, pe) : ce;   // small may extend past pe (owned)
        float acc = cell_accum(plist2, feat_t, p, b2, lane);
        int bb   = fc >= NCELL;
        int cell = fc - bb*NCELL;
        float* addr = out + ((size_t)(bb*C_ + lane))*NCELL + cell;
        if (big) atomicAdd(addr, acc);
        else     *addr = acc;
        p = ce;
    }
}

extern "C" void kernel_launch(void* const* d_in, const int* in_sizes, int n_in,
                              void* d_out, int out_size, void* d_ws, size_t ws_size,
                              hipStream_t stream) {
    const float* feat  = (const float*)d_in[0];
    const float* intr  = (const float*)d_in[1];
    const float* ext   = (const float*)d_in[2];
    const float* w1    = (const float*)d_in[3];
    const float* b1    = (const float*)d_in[4];
    const float* gamma = (const float*)d_in[5];
    const float* beta  = (const float*)d_in[6];
    const float* rmean = (const float*)d_in[7];
    const float* rvar  = (const float*)d_in[8];
    const float* w2    = (const float*)d_in[9];
    const float* b2    = (const float*)d_in[10];
    float* out = (float*)d_out;
    (void)in_sizes; (void)n_in; (void)out_size; (void)ws_size;

    // workspace layout (plist2 first for 8B alignment); total ~9.5 MB
    int2*  plist2 = (int2*)d_ws;                    // NPTS int2 = 4.33 MB
    float* w1t    = (float*)(plist2 + NPTS);        // 36864
    float* w2t    = w1t + C_*C_*9;                  // 4096
    float* bns    = w2t + D_*C_;                    // 64
    float* bnsh   = bns + C_;                       // 64
    float* kinv   = bnsh + C_;                      // 108
    float* probs  = kinv + BN_*9;                   // 540672
    float* feat_t = probs + NPTS;                   // 540672
    int*   startp = (int*)(feat_t + NPTS);          // 80001
    int*   cursor = startp + (NBCELL + 1);          // 80000
    int*   bsum   = cursor + NBCELL;                // 313

    // ---- 7-launch pipeline ----
    setup_kernel<<<NB_SETUP, 256, 0, stream>>>(feat, w1, w2, gamma, beta,
                                               rmean, rvar, intr, out, startp,
                                               w1t, w2t, bns, bnsh, kinv, feat_t);
    enc_kernel<<<528, 256, 0, stream>>>(feat_t, w1t, w2t, bns, bnsh, b1, b2, probs);
    geomhist_kernel<<<NPTS/256, 256, 0, stream>>>(ext, kinv, startp + 1);
    scanA_kernel<<<NSCANB, 256, 0, stream>>>(startp, cursor, bsum);
    scanC_kernel<<<(NBCELL + 511)/512, 512, 0, stream>>>(startp, cursor, bsum);
    geomscatter_kernel<<<SCBLK, 256, 0, stream>>>(ext, kinv, probs, cursor, plist2);
    gather4_kernel<<<GBLK, 256, 0, stream>>>(feat_t, startp, plist2, out);
}

// Round 20
// 184.840 us; speedup vs baseline: 1.1847x; 1.0203x over previous
//
#include <hip/hip_runtime.h>
#include <math.h>

#define B_   2
#define N_   6
#define C_   64
#define D_   64
#define FH_  16
#define FW_  44
#define BN_  (B_*N_)              // 12
#define PIX_ (FH_*FW_)            // 704
#define NPIX (BN_*PIX_)           // 8448
#define NPTS (BN_*D_*PIX_)        // 540672
#define PPBN (D_*PIX_)            // 45056 points per (b,n) image
#define BEVH 200
#define BEVW 200
#define NCELL (BEVH*BEVW)         // 40000
#define NBCELL (B_*NCELL)         // 80000
#define NSCANB ((NBCELL + 255)/256)  // 313 scan blocks
#define PPW  64                   // points per wave in gather
#define GBLK (NPTS/(PPW*4))       // 2112 gather blocks (4 waves each)
#define NXCD 8
#define GCHUNK (GBLK/NXCD)        // 264 (2112 % 8 == 0 -> bijective swizzle)
#define SCBLK (NPTS/256)          // 2112 scatter blocks (same swizzle)
// record pack: pixg (14 bits, max 8447) | fc << 14 (17 bits, max 79999) -> <2^31

// setup mega-kernel block ranges
#define NB_ZOUT 5000              // zero target: 5.12M f32 = 1.28M float4
#define NB_ZSP  313               // startp zero (80001 ints)
#define NB_TW   160               // weight transposes (40960 elems)
#define NB_PREP 1                 // BN affine + Kinv
#define NB_FT   132               // feat transpose
#define NB_SETUP (NB_ZOUT + NB_ZSP + NB_TW + NB_PREP + NB_FT)   // 5606

// ---------------- setup: zero zt + zero startp + transW + prep + featT -----
// zt = out (direct path) or out_t (staged path); both are 5.12M floats.
__global__ __launch_bounds__(256) void setup_kernel(
        const float* __restrict__ feat, const float* __restrict__ w1,
        const float* __restrict__ w2,
        const float* __restrict__ gamma, const float* __restrict__ beta,
        const float* __restrict__ rmean, const float* __restrict__ rvar,
        const float* __restrict__ intr,
        float* __restrict__ zt, int* __restrict__ startp,
        float* __restrict__ w1t, float* __restrict__ w2t,
        float* __restrict__ bns, float* __restrict__ bnsh,
        float* __restrict__ kinv, float* __restrict__ feat_t) {
#pragma clang fp contract(off)
    __shared__ float lds[64][65];
    int blk = blockIdx.x;
    int t   = threadIdx.x;

    if (blk < NB_ZOUT) {
        ((float4*)zt)[blk*256 + t] = float4{0.f, 0.f, 0.f, 0.f};
        return;
    }
    blk -= NB_ZOUT;
    if (blk < NB_ZSP) {
        int i = blk*256 + t;
        if (i < NBCELL + 1) startp[i] = 0;
        return;
    }
    blk -= NB_ZSP;
    if (blk < NB_TW) {
        int idx = blk*256 + t;
        if (idx < C_*C_*9) {
            int cout = idx / (C_*9);
            int r    = idx % (C_*9);
            int cin  = r / 9;
            int tap  = r % 9;
            w1t[(((cin >> 4)*9 + tap)*64 + cout)*16 + (cin & 15)] = w1[idx];
        } else if (idx < C_*C_*9 + D_*C_) {
            int j = idx - C_*C_*9;
            int d = j / C_, c = j % C_;
            w2t[c*D_ + d] = w2[j];
        }
        return;
    }
    blk -= NB_TW;
    if (blk < NB_PREP) {
        if (t < C_) {
            float s = gamma[t] / sqrtf(rvar[t] + 1e-5f);
            bns[t]  = s;
            bnsh[t] = beta[t] - rmean[t] * s;
        }
        if (t < BN_) {
            const float* K = intr + t*9;
            float A[3][3];
            for (int r = 0; r < 3; r++)
                for (int cc = 0; cc < 3; cc++) A[r][cc] = K[r*3 + cc];
            int ipiv[3];
            // sgetf2
            for (int j = 0; j < 3; j++) {
                int p = j; float mx = fabsf(A[j][j]);
                for (int i = j+1; i < 3; i++) {
                    float v = fabsf(A[i][j]);
                    if (v > mx) { mx = v; p = i; }
                }
                ipiv[j] = p;
                if (p != j)
                    for (int k = 0; k < 3; k++) { float tm = A[j][k]; A[j][k] = A[p][k]; A[p][k] = tm; }
                float rpiv = 1.0f / A[j][j];
                for (int i = j+1; i < 3; i++) A[i][j] = A[i][j] * rpiv;
                for (int k = j+1; k < 3; k++)
                    for (int i = j+1; i < 3; i++)
                        A[i][k] = A[i][k] - A[i][j] * A[j][k];
            }
            // strti2
            for (int j = 0; j < 3; j++) {
                float ajj = 1.0f / A[j][j];
                A[j][j] = ajj;
                float najj = -ajj;
                for (int jj = 0; jj < j; jj++) {
                    float temp = A[jj][j];
                    for (int i = 0; i < jj; i++) A[i][j] = A[i][j] + temp * A[i][jj];
                    A[jj][j] = A[jj][j] * A[jj][jj];
                }
                for (int i = 0; i < j; i++) A[i][j] = A[i][j] * najj;
            }
            // sgetri
            for (int j = 1; j >= 0; j--) {
                float work[3];
                for (int i = j+1; i < 3; i++) { work[i] = A[i][j]; A[i][j] = 0.0f; }
                for (int k = j+1; k < 3; k++)
                    for (int i = 0; i < 3; i++)
                        A[i][j] = A[i][j] - A[i][k] * work[k];
            }
            for (int j = 2; j >= 0; j--) {
                int p = ipiv[j];
                if (p != j)
                    for (int i = 0; i < 3; i++) { float tm = A[i][j]; A[i][j] = A[i][p]; A[i][p] = tm; }
            }
            for (int k = 0; k < 9; k++) kinv[t*9 + k] = A[k/3][k%3];
        }
        return;
    }
    blk -= NB_PREP;
    // featT: [bn][c][pix] -> [bn*704+pix][c]
    {
        int bn   = blk / 11;
        int pb   = (blk % 11) * 64;
        int lane = t & 63;
        int r0   = t >> 6;
#pragma unroll
        for (int rr = 0; rr < 16; rr++) {
            int c = r0 + 4*rr;
            lds[c][lane] = feat[((size_t)bn*C_ + c)*PIX_ + pb + lane];
        }
        __syncthreads();
#pragma unroll
        for (int rr = 0; rr < 16; rr++) {
            int pr = r0 + 4*rr;
            feat_t[((size_t)bn*PIX_ + pb + pr)*C_ + lane] = lds[lane][pr];
        }
    }
}

// ---------------- enc v5: b128 LDS reads (4-ci weight/feature vectors) ------
__global__ __launch_bounds__(256) void enc_kernel(
        const float* __restrict__ feat_t,
        const float* __restrict__ w1t, const float* __restrict__ w2t,
        const float* __restrict__ bns, const float* __restrict__ bnsh,
        const float* __restrict__ b1,  const float* __restrict__ b2,
        float* __restrict__ probs) {
    __shared__ float wlds[9*C_*16];    // 36 KB: one 16-ci weight chunk
    __shared__ float flds[36][C_];     // 9 KB: 6x6 pixel window x 64 chan
    __shared__ float hl[16][C_];       // 4 KB
    int blk = blockIdx.x;              // 0..527
    int bn  = blk / 44;
    int rem = blk % 44;
    int yt  = rem / 11;
    int xt  = rem % 11;
    int t   = threadIdx.x;
    int c   = t & 63;
    int w   = __builtin_amdgcn_readfirstlane(t >> 6);   // wave id 0..3
    int y0  = yt*4;
    int x0  = xt*4;
    int y   = y0 + w;

    // stage feature window (zero-padded halo), coalesced from feat_t
    for (int s = w; s < 36; s += 4) {
        int srow = s / 6, scol = s % 6;
        int grow = y0 - 1 + srow;
        int gcol = x0 - 1 + scol;
        float v = 0.f;
        if (grow >= 0 && grow < FH_ && gcol >= 0 && gcol < FW_)
            v = feat_t[((size_t)bn*PIX_ + grow*FW_ + gcol)*C_ + c];
        flds[s][c] = v;
    }

    float h0 = b1[c], h1 = h0, h2 = h0, h3 = h0;

    for (int cc16 = 0; cc16 < 4; cc16++) {
        __syncthreads();               // covers flds (1st iter) + wlds reuse
        {
            const float4* s4 = (const float4*)(w1t + cc16*(9*C_*16));
            float4* d4 = (float4*)wlds;
#pragma unroll
            for (int i = 0; i < 9; i++)
                d4[t + 256*i] = s4[t + 256*i];
        }
        __syncthreads();
        int cc = cc16*16;
#pragma unroll
        for (int cg = 0; cg < 16; cg += 4) {
            float4 wv4[9];
#pragma unroll
            for (int tap = 0; tap < 9; tap++)
                wv4[tap] = *(const float4*)&wlds[(tap*64 + c)*16 + cg];
            float4 fr4[3][6];
#pragma unroll
            for (int r = 0; r < 3; r++)
#pragma unroll
                for (int cl = 0; cl < 6; cl++)
                    fr4[r][cl] = *(const float4*)&flds[(w + r)*6 + cl][cc + cg];
#pragma unroll
            for (int k = 0; k < 4; k++) {
#pragma unroll
                for (int ky = 0; ky < 3; ky++) {
#pragma unroll
                    for (int kx = 0; kx < 3; kx++) {
                        float wv = ((const float*)&wv4[ky*3 + kx])[k];
                        h0 = fmaf(wv, ((const float*)&fr4[ky][kx + 0])[k], h0);
                        h1 = fmaf(wv, ((const float*)&fr4[ky][kx + 1])[k], h1);
                        h2 = fmaf(wv, ((const float*)&fr4[ky][kx + 2])[k], h2);
                        h3 = fmaf(wv, ((const float*)&fr4[ky][kx + 3])[k], h3);
                    }
                }
            }
        }
    }

    float sc = bns[c], sh = bnsh[c];
    {
        float v0 = fmaf(h0, sc, sh); hl[w*4 + 0][c] = v0 > 0.f ? v0 : 0.f;
        float v1 = fmaf(h1, sc, sh); hl[w*4 + 1][c] = v1 > 0.f ? v1 : 0.f;
        float v2 = fmaf(h2, sc, sh); hl[w*4 + 2][c] = v2 > 0.f ? v2 : 0.f;
        float v3 = fmaf(h3, sc, sh); hl[w*4 + 3][c] = v3 > 0.f ? v3 : 0.f;
    }
    __syncthreads();

    float l0 = b2[c], l1 = l0, l2 = l0, l3 = l0;
    for (int c2 = 0; c2 < C_; c2++) {
        float wv = w2t[c2*D_ + c];
        l0 = fmaf(wv, hl[w*4 + 0][c2], l0);
        l1 = fmaf(wv, hl[w*4 + 1][c2], l1);
        l2 = fmaf(wv, hl[w*4 + 2][c2], l2);
        l3 = fmaf(wv, hl[w*4 + 3][c2], l3);
    }

    float lv[4] = {l0, l1, l2, l3};
#pragma unroll
    for (int p = 0; p < 4; p++) {
        float l = lv[p];
        float m = l;
        for (int off = 32; off; off >>= 1) m = fmaxf(m, __shfl_xor(m, off));
        float e = expf(l - m);
        float s = e;
        for (int off = 32; off; off >>= 1) s += __shfl_xor(s, off);
        probs[((size_t)bn*PIX_ + y*FW_ + x0 + p)*D_ + c] = e / s;
    }
}

// ---------------- geometry: cell for point i (f32 chain, validated r4) ------
__device__ __forceinline__ int compute_cell(int i, const float* __restrict__ kinv,
                                            const float* __restrict__ ext) {
#pragma clang fp contract(off)
    int x  = i % FW_;
    int y  = (i / FW_) % FH_;
    int d  = (i / PIX_) % D_;
    int bn = i / PPBN;

    const float* kv = kinv + bn*9;
    const float* e  = ext  + bn*16;

    float u  = (x == FW_-1) ? 703.0f : (float)((double)x * (703.0/43.0));
    float vv = (float)((double)y * 17.0);
    float dd = (d == D_-1) ? 60.0f  : (float)(1.0 + (double)d * (59.0/63.0));

    float px = u * dd;
    float py = vv * dd;
    float pz = dd;

    float cx = (kv[0]*px + kv[1]*py) + kv[2]*pz;
    float cy = (kv[3]*px + kv[4]*py) + kv[5]*pz;
    float cz = (kv[6]*px + kv[7]*py) + kv[8]*pz;

    float ex = (e[0]*cx + e[1]*cy) + e[2]*cz;
    float ey = (e[4]*cx + e[5]*cy) + e[6]*cz;
    ex = ex + e[3];
    ey = ey + e[7];

    float gx = (ex + 50.0f) / 0.5f;
    float gy = (ey + 50.0f) / 0.5f;
    int ix = (int)floorf(gx);
    int iy = (int)floorf(gy);
    return (ix >= 0 && ix < BEVW && iy >= 0 && iy < BEVH) ? (iy*BEVW + ix) : -1;
}

// ---- wave run-aggregation helpers ----
__device__ __forceinline__ void run_info(int fc, int lane,
                                         bool& isLeader, int& runLen, int& lead) {
    int prev = __shfl_up(fc, 1);
    isLeader = (lane == 0) || (fc != prev);
    unsigned long long mask = __ballot(isLeader);
    unsigned long long hi = (lane == 63) ? 0ull : (mask >> (lane + 1));
    int next = hi ? (lane + 1 + __builtin_ctzll(hi)) : 64;
    runLen = next - lane;
    unsigned long long lo = mask & (~0ull >> (63 - lane));
    lead = 63 - __builtin_clzll(lo);
}

// ---------------- geom + histogram (wave-aggregated, no LDS) ----------------
__global__ __launch_bounds__(256) void geomhist_kernel(
        const float* __restrict__ ext, const float* __restrict__ kinv,
        int* __restrict__ counts) {
    int i = blockIdx.x * 256 + threadIdx.x;
    int lane = threadIdx.x & 63;
    int fc = -1;
    if (i < NPTS) {
        int cell = compute_cell(i, kinv, ext);
        if (cell >= 0) fc = (i / (PPBN * N_)) * NCELL + cell;
    }
    bool isLeader; int runLen, lead;
    run_info(fc, lane, isLeader, runLen, lead);
    if (isLeader && fc >= 0) atomicAdd(&counts[fc], runLen);
}

// ---------------- scanA: block-local scan ----------------
__global__ __launch_bounds__(256) void scanA_kernel(
        int* __restrict__ startp, int* __restrict__ cursor, int* __restrict__ bsum) {
    __shared__ int sdata[256];
    int t = threadIdx.x;
    int i = blockIdx.x * 256 + t;
    int v = (i < NBCELL) ? startp[1 + i] : 0;
    sdata[t] = v;
    __syncthreads();
#pragma unroll
    for (int off = 1; off < 256; off <<= 1) {
        int add = (t >= off) ? sdata[t - off] : 0;
        __syncthreads();
        sdata[t] += add;
        __syncthreads();
    }
    if (i < NBCELL) {
        startp[1 + i] = sdata[t];
        cursor[i]     = sdata[t] - v;
    }
    if (t == 255) bsum[blockIdx.x] = sdata[255];
}

// ---------------- scanC': re-scan bsum in LDS + apply offsets ---------------
__global__ __launch_bounds__(512) void scanC_kernel(
        int* __restrict__ startp, int* __restrict__ cursor,
        const int* __restrict__ bsum) {
    __shared__ int sdata[512];
    int t = threadIdx.x;
    int v = (t < NSCANB) ? bsum[t] : 0;
    sdata[t] = v;
    __syncthreads();
#pragma unroll
    for (int off = 1; off < 512; off <<= 1) {
        int add = (t >= off) ? sdata[t - off] : 0;
        __syncthreads();
        sdata[t] += add;
        __syncthreads();
    }
    int i = blockIdx.x * 512 + t;
    if (i >= NBCELL) return;
    int j = i >> 8;                       // which scanA block
    int off = (j == 0) ? 0 : sdata[j - 1];
    startp[1 + i] += off;
    cursor[i]     += off;
}

// ---------------- geom + scatter packed records (wave-aggregated, XCD-swz) --
// record: .x = prob bits, .y = pixg | (fc << 14)
__global__ __launch_bounds__(256) void geomscatter_kernel(
        const float* __restrict__ ext, const float* __restrict__ kinv,
        const float* __restrict__ probs,
        int* __restrict__ cursor, int2* __restrict__ plist2) {
    int blk = (blockIdx.x % NXCD) * (SCBLK/NXCD) + blockIdx.x / NXCD;
    int i = blk * 256 + threadIdx.x;
    int lane = threadIdx.x & 63;
    int fc = -1, pixg = 0;
    float pr = 0.f;
    if (i < NPTS) {
        int cell = compute_cell(i, kinv, ext);
        if (cell >= 0) {
            int pix = i % PIX_;
            int d   = (i / PIX_) % D_;
            int bn  = i / PPBN;
            fc   = (bn / N_) * NCELL + cell;
            pixg = bn*PIX_ + pix;
            pr   = probs[(size_t)pixg*D_ + d];
        }
    }
    bool isLeader; int runLen, lead;
    run_info(fc, lane, isLeader, runLen, lead);
    int base = 0;
    if (isLeader && fc >= 0) base = atomicAdd(&cursor[fc], runLen);
    base = __shfl(base, lead);
    if (fc >= 0)
        plist2[base + (lane - lead)] = make_int2(__float_as_int(pr),
                                                 pixg | (fc << 14));
}

// ---- 4-way ILP cell accumulation: 4 independent FMA chains, loads batched --
__device__ __forceinline__ float cell_accum(
        const int2* __restrict__ plist2, const float* __restrict__ feat_t,
        int q0, int q1, int lane) {
    float a0 = 0.f, a1 = 0.f, a2 = 0.f, a3 = 0.f;
    int q = q0;
    for (; q + 4 <= q1; q += 4) {
        int2 r0 = plist2[q];
        int2 r1 = plist2[q + 1];
        int2 r2 = plist2[q + 2];
        int2 r3 = plist2[q + 3];
        float f0 = feat_t[(size_t)(r0.y & 0x3FFF)*C_ + lane];
        float f1 = feat_t[(size_t)(r1.y & 0x3FFF)*C_ + lane];
        float f2 = feat_t[(size_t)(r2.y & 0x3FFF)*C_ + lane];
        float f3 = feat_t[(size_t)(r3.y & 0x3FFF)*C_ + lane];
        a0 = fmaf(__int_as_float(r0.x), f0, a0);
        a1 = fmaf(__int_as_float(r1.x), f1, a1);
        a2 = fmaf(__int_as_float(r2.x), f2, a2);
        a3 = fmaf(__int_as_float(r3.x), f3, a3);
    }
    for (; q < q1; q++) {
        int2 r = plist2[q];
        a0 = fmaf(__int_as_float(r.x),
                  feat_t[(size_t)(r.y & 0x3FFF)*C_ + lane], a0);
    }
    return (a0 + a1) + (a2 + a3);
}

// ---------------- gather4s: staged (cell-major out_t, coalesced flushes) ----
__global__ __launch_bounds__(256) void gather4s_kernel(
        const float* __restrict__ feat_t, const int* __restrict__ startp,
        const int2* __restrict__ plist2, float* __restrict__ out_t) {
    int blk  = (blockIdx.x % NXCD) * GCHUNK + blockIdx.x / NXCD;
    int gid  = blk * 256 + threadIdx.x;
    int W    = gid >> 6;
    int lane = gid & 63;
    int total = startp[NBCELL];
    int p0 = W * PPW;
    if (p0 >= total) return;
    int pe = min(p0 + PPW, total);
    int p  = p0;

    // head: cell continuing from a previous wave's range
    {
        int2 r = plist2[p0];
        int fc = ((unsigned)r.y) >> 14;
        int cs = startp[fc], ce = startp[fc + 1];
        if (cs < p0) {
            if (ce - cs > 2*PPW) {        // big: process our slice
                float acc = cell_accum(plist2, feat_t, p0, min(pe, ce), lane);
                atomicAdd(out_t + (size_t)fc*C_ + lane, acc);
            }
            p = ce;                        // small: skip (owned upstream)
        }
    }
    // cells starting in [p, pe)
    while (p < pe) {
        int2 r = plist2[p];
        int fc = ((unsigned)r.y) >> 14;
        int ce = startp[fc + 1];
        bool big = (ce - p > 2*PPW);
        int b2 = big ? min(ce, pe) : ce;   // small may extend past pe (owned)
        float acc = cell_accum(plist2, feat_t, p, b2, lane);
        float* addr = out_t + (size_t)fc*C_ + lane;   // 256B contiguous/wave
        if (big) atomicAdd(addr, acc);
        else     *addr = acc;
        p = ce;
    }
}

// ---------------- transT: out_t[fc][chan] -> out[b][chan][cell] -------------
// 1250 blocks x 256 thr; block = 64 consecutive cells of one batch (625/batch).
__global__ __launch_bounds__(256) void transT_kernel(
        const float* __restrict__ out_t, float* __restrict__ out) {
    __shared__ float lds[64][65];
    int blk   = blockIdx.x;               // 0..1249
    int b     = blk / (NCELL/64);         // 625 tiles per batch
    int cell0 = (blk % (NCELL/64)) * 64;
    int t     = threadIdx.x;
    int lane  = t & 63;
    int r0    = t >> 6;
    size_t fcb = (size_t)b*NCELL + cell0;
#pragma unroll
    for (int k = 0; k < 16; k++) {
        int r = r0 + 4*k;                 // cell offset in tile
        lds[r][lane] = out_t[(fcb + r)*C_ + lane];
    }
    __syncthreads();
#pragma unroll
    for (int k = 0; k < 16; k++) {
        int ch = r0 + 4*k;
        out[((size_t)(b*C_ + ch))*NCELL + cell0 + lane] = lds[lane][ch];
    }
}

// ---------------- gather4d: direct-write fallback (r19, proven) -------------
__global__ __launch_bounds__(256) void gather4d_kernel(
        const float* __restrict__ feat_t, const int* __restrict__ startp,
        const int2* __restrict__ plist2, float* __restrict__ out) {
    int blk  = (blockIdx.x % NXCD) * GCHUNK + blockIdx.x / NXCD;
    int gid  = blk * 256 + threadIdx.x;
    int W    = gid >> 6;
    int lane = gid & 63;
    int total = startp[NBCELL];
    int p0 = W * PPW;
    if (p0 >= total) return;
    int pe = min(p0 + PPW, total);
    int p  = p0;

    {
        int2 r = plist2[p0];
        int fc = ((unsigned)r.y) >> 14;
        int cs = startp[fc], ce = startp[fc + 1];
        if (cs < p0) {
            if (ce - cs > 2*PPW) {
                float acc = cell_accum(plist2, feat_t, p0, min(pe, ce), lane);
                int bb   = fc >= NCELL;
                int cell = fc - bb*NCELL;
                atomicAdd(out + ((size_t)(bb*C_ + lane))*NCELL + cell, acc);
            }
            p = ce;
        }
    }
    while (p < pe) {
        int2 r = plist2[p];
        int fc = ((unsigned)r.y) >> 14;
        int ce = startp[fc + 1];
        bool big = (ce - p > 2*PPW);
        int b2 = big ? min(ce, pe) : ce;
        float acc = cell_accum(plist2, feat_t, p, b2, lane);
        int bb   = fc >= NCELL;
        int cell = fc - bb*NCELL;
        float* addr = out + ((size_t)(bb*C_ + lane))*NCELL + cell;
        if (big) atomicAdd(addr, acc);
        else     *addr = acc;
        p = ce;
    }
}

extern "C" void kernel_launch(void* const* d_in, const int* in_sizes, int n_in,
                              void* d_out, int out_size, void* d_ws, size_t ws_size,
                              hipStream_t stream) {
    const float* feat  = (const float*)d_in[0];
    const float* intr  = (const float*)d_in[1];
    const float* ext   = (const float*)d_in[2];
    const float* w1    = (const float*)d_in[3];
    const float* b1    = (const float*)d_in[4];
    const float* gamma = (const float*)d_in[5];
    const float* beta  = (const float*)d_in[6];
    const float* rmean = (const float*)d_in[7];
    const float* rvar  = (const float*)d_in[8];
    const float* w2    = (const float*)d_in[9];
    const float* b2    = (const float*)d_in[10];
    float* out = (float*)d_out;
    (void)in_sizes; (void)n_in; (void)out_size;

    // workspace layout (plist2 first for 8B alignment)
    int2*  plist2 = (int2*)d_ws;                    // NPTS int2 = 4.33 MB
    float* w1t    = (float*)(plist2 + NPTS);        // 36864
    float* w2t    = w1t + C_*C_*9;                  // 4096
    float* bns    = w2t + D_*C_;                    // 64
    float* bnsh   = bns + C_;                       // 64
    float* kinv   = bnsh + C_;                      // 108
    float* probs  = kinv + BN_*9;                   // 540672
    float* feat_t = probs + NPTS;                   // 540672
    int*   startp = (int*)(feat_t + NPTS);          // 80001
    int*   cursor = startp + (NBCELL + 1);          // 80000
    int*   bsum   = cursor + NBCELL;                // 313
    float* out_t  = (float*)(bsum + NSCANB);        // NBCELL*C_ = 20.5 MB
    size_t need   = (size_t)((char*)(out_t + (size_t)NBCELL*C_) - (char*)d_ws);
    bool staged   = (ws_size >= need);

    float* zt = staged ? out_t : out;   // zero target in setup

    setup_kernel<<<NB_SETUP, 256, 0, stream>>>(feat, w1, w2, gamma, beta,
                                               rmean, rvar, intr, zt, startp,
                                               w1t, w2t, bns, bnsh, kinv, feat_t);
    enc_kernel<<<528, 256, 0, stream>>>(feat_t, w1t, w2t, bns, bnsh, b1, b2, probs);
    geomhist_kernel<<<NPTS/256, 256, 0, stream>>>(ext, kinv, startp + 1);
    scanA_kernel<<<NSCANB, 256, 0, stream>>>(startp, cursor, bsum);
    scanC_kernel<<<(NBCELL + 511)/512, 512, 0, stream>>>(startp, cursor, bsum);
    geomscatter_kernel<<<SCBLK, 256, 0, stream>>>(ext, kinv, probs, cursor, plist2);
    if (staged) {
        gather4s_kernel<<<GBLK, 256, 0, stream>>>(feat_t, startp, plist2, out_t);
        transT_kernel<<<NBCELL/64, 256, 0, stream>>>(out_t, out);
    } else {
        gather4d_kernel<<<GBLK, 256, 0, stream>>>(feat_t, startp, plist2, out);
    }
}

// Round 21
// 176.382 us; speedup vs baseline: 1.2415x; 1.0480x over previous
//
#include <hip/hip_runtime.h>
#include <math.h>

#define B_   2
#define N_   6
#define C_   64
#define D_   64
#define FH_  16
#define FW_  44
#define BN_  (B_*N_)              // 12
#define PIX_ (FH_*FW_)            // 704
#define NPIX (BN_*PIX_)           // 8448
#define NPTS (BN_*D_*PIX_)        // 540672
#define PPBN (D_*PIX_)            // 45056 points per (b,n) image
#define BEVH 200
#define BEVW 200
#define NCELL (BEVH*BEVW)         // 40000
#define NBCELL (B_*NCELL)         // 80000
#define NSCANB ((NBCELL + 255)/256)  // 313 scan blocks
#define PPW  64                   // points per wave in gather
#define GBLK (NPTS/(PPW*4))       // 2112 gather blocks (4 waves each)
#define NXCD 8
#define GCHUNK (GBLK/NXCD)        // 264 (2112 % 8 == 0 -> bijective swizzle)
#define SCBLK (NPTS/256)          // 2112 scatter blocks (same swizzle)
// record pack: pixg (14 bits, max 8447) | fc << 14 (17 bits, max 79999) -> <2^31

// setup mega-kernel block ranges
#define NB_ZOUT 5000              // zero target: 5.12M f32 = 1.28M float4
#define NB_ZSP  313               // startp zero (80001 ints)
#define NB_TW   160               // weight transposes (40960 elems)
#define NB_PREP 1                 // BN affine + Kinv
#define NB_FT   132               // feat transpose
#define NB_SETUP (NB_ZOUT + NB_ZSP + NB_TW + NB_PREP + NB_FT)   // 5606

// ---------------- setup: zero zt + zero startp + transW + prep + featT -----
// w1t layout (bank-conflict-free b128 enc reads):
//   [cin-chunk(4)][tap(9)][g4 = (cin%16)/4 (4)][cout(64)][cin%4 (4)]
// enc reads float4 at ((tap*4+g4)*64 + cout)*4 -> lane stride 16B (stride-1
// b128 pattern, conflict-free). r20 layout had lane stride 64B -> 16-way
// conflict (3.65M SQ_LDS_BANK_CONFLICT).
__global__ __launch_bounds__(256) void setup_kernel(
        const float* __restrict__ feat, const float* __restrict__ w1,
        const float* __restrict__ w2,
        const float* __restrict__ gamma, const float* __restrict__ beta,
        const float* __restrict__ rmean, const float* __restrict__ rvar,
        const float* __restrict__ intr,
        float* __restrict__ zt, int* __restrict__ startp,
        float* __restrict__ w1t, float* __restrict__ w2t,
        float* __restrict__ bns, float* __restrict__ bnsh,
        float* __restrict__ kinv, float* __restrict__ feat_t) {
#pragma clang fp contract(off)
    __shared__ float lds[64][65];
    int blk = blockIdx.x;
    int t   = threadIdx.x;

    if (blk < NB_ZOUT) {
        ((float4*)zt)[blk*256 + t] = float4{0.f, 0.f, 0.f, 0.f};
        return;
    }
    blk -= NB_ZOUT;
    if (blk < NB_ZSP) {
        int i = blk*256 + t;
        if (i < NBCELL + 1) startp[i] = 0;
        return;
    }
    blk -= NB_ZSP;
    if (blk < NB_TW) {
        int idx = blk*256 + t;
        if (idx < C_*C_*9) {
            int cout  = idx / (C_*9);
            int r     = idx % (C_*9);
            int cin   = r / 9;
            int tap   = r % 9;
            int chunk = cin >> 4;
            int g4    = (cin & 15) >> 2;
            int l4    = cin & 3;
            w1t[((((chunk*9 + tap)*4 + g4)*64 + cout)*4) + l4] = w1[idx];
        } else if (idx < C_*C_*9 + D_*C_) {
            int j = idx - C_*C_*9;
            int d = j / C_, c = j % C_;
            w2t[c*D_ + d] = w2[j];
        }
        return;
    }
    blk -= NB_TW;
    if (blk < NB_PREP) {
        if (t < C_) {
            float s = gamma[t] / sqrtf(rvar[t] + 1e-5f);
            bns[t]  = s;
            bnsh[t] = beta[t] - rmean[t] * s;
        }
        if (t < BN_) {
            const float* K = intr + t*9;
            float A[3][3];
            for (int r = 0; r < 3; r++)
                for (int cc = 0; cc < 3; cc++) A[r][cc] = K[r*3 + cc];
            int ipiv[3];
            // sgetf2
            for (int j = 0; j < 3; j++) {
                int p = j; float mx = fabsf(A[j][j]);
                for (int i = j+1; i < 3; i++) {
                    float v = fabsf(A[i][j]);
                    if (v > mx) { mx = v; p = i; }
                }
                ipiv[j] = p;
                if (p != j)
                    for (int k = 0; k < 3; k++) { float tm = A[j][k]; A[j][k] = A[p][k]; A[p][k] = tm; }
                float rpiv = 1.0f / A[j][j];
                for (int i = j+1; i < 3; i++) A[i][j] = A[i][j] * rpiv;
                for (int k = j+1; k < 3; k++)
                    for (int i = j+1; i < 3; i++)
                        A[i][k] = A[i][k] - A[i][j] * A[j][k];
            }
            // strti2
            for (int j = 0; j < 3; j++) {
                float ajj = 1.0f / A[j][j];
                A[j][j] = ajj;
                float najj = -ajj;
                for (int jj = 0; jj < j; jj++) {
                    float temp = A[jj][j];
                    for (int i = 0; i < jj; i++) A[i][j] = A[i][j] + temp * A[i][jj];
                    A[jj][j] = A[jj][j] * A[jj][jj];
                }
                for (int i = 0; i < j; i++) A[i][j] = A[i][j] * najj;
            }
            // sgetri
            for (int j = 1; j >= 0; j--) {
                float work[3];
                for (int i = j+1; i < 3; i++) { work[i] = A[i][j]; A[i][j] = 0.0f; }
                for (int k = j+1; k < 3; k++)
                    for (int i = 0; i < 3; i++)
                        A[i][j] = A[i][j] - A[i][k] * work[k];
            }
            for (int j = 2; j >= 0; j--) {
                int p = ipiv[j];
                if (p != j)
                    for (int i = 0; i < 3; i++) { float tm = A[i][j]; A[i][j] = A[i][p]; A[i][p] = tm; }
            }
            for (int k = 0; k < 9; k++) kinv[t*9 + k] = A[k/3][k%3];
        }
        return;
    }
    blk -= NB_PREP;
    // featT: [bn][c][pix] -> [bn*704+pix][c]
    {
        int bn   = blk / 11;
        int pb   = (blk % 11) * 64;
        int lane = t & 63;
        int r0   = t >> 6;
#pragma unroll
        for (int rr = 0; rr < 16; rr++) {
            int c = r0 + 4*rr;
            lds[c][lane] = feat[((size_t)bn*C_ + c)*PIX_ + pb + lane];
        }
        __syncthreads();
#pragma unroll
        for (int rr = 0; rr < 16; rr++) {
            int pr = r0 + 4*rr;
            feat_t[((size_t)bn*PIX_ + pb + pr)*C_ + lane] = lds[lane][pr];
        }
    }
}

// ---------------- enc v6: conflict-free b128 weight reads -------------------
__global__ __launch_bounds__(256) void enc_kernel(
        const float* __restrict__ feat_t,
        const float* __restrict__ w1t, const float* __restrict__ w2t,
        const float* __restrict__ bns, const float* __restrict__ bnsh,
        const float* __restrict__ b1,  const float* __restrict__ b2,
        float* __restrict__ probs) {
    __shared__ float wlds[9*C_*16];    // 36 KB: one 16-ci weight chunk
    __shared__ float flds[36][C_];     // 9 KB: 6x6 pixel window x 64 chan
    __shared__ float hl[16][C_];       // 4 KB
    int blk = blockIdx.x;              // 0..527
    int bn  = blk / 44;
    int rem = blk % 44;
    int yt  = rem / 11;
    int xt  = rem % 11;
    int t   = threadIdx.x;
    int c   = t & 63;
    int w   = __builtin_amdgcn_readfirstlane(t >> 6);   // wave id 0..3
    int y0  = yt*4;
    int x0  = xt*4;
    int y   = y0 + w;

    // stage feature window (zero-padded halo), coalesced from feat_t
    for (int s = w; s < 36; s += 4) {
        int srow = s / 6, scol = s % 6;
        int grow = y0 - 1 + srow;
        int gcol = x0 - 1 + scol;
        float v = 0.f;
        if (grow >= 0 && grow < FH_ && gcol >= 0 && gcol < FW_)
            v = feat_t[((size_t)bn*PIX_ + grow*FW_ + gcol)*C_ + c];
        flds[s][c] = v;
    }

    float h0 = b1[c], h1 = h0, h2 = h0, h3 = h0;

    for (int cc16 = 0; cc16 < 4; cc16++) {
        __syncthreads();               // covers flds (1st iter) + wlds reuse
        {
            const float4* s4 = (const float4*)(w1t + cc16*(9*C_*16));
            float4* d4 = (float4*)wlds;
#pragma unroll
            for (int i = 0; i < 9; i++)
                d4[t + 256*i] = s4[t + 256*i];
        }
        __syncthreads();
        int cc = cc16*16;
#pragma unroll
        for (int g4 = 0; g4 < 4; g4++) {
            float4 wv4[9];
#pragma unroll
            for (int tap = 0; tap < 9; tap++)
                wv4[tap] = *(const float4*)&wlds[((tap*4 + g4)*64 + c)*4];
            float4 fr4[3][6];
#pragma unroll
            for (int r = 0; r < 3; r++)
#pragma unroll
                for (int cl = 0; cl < 6; cl++)
                    fr4[r][cl] = *(const float4*)&flds[(w + r)*6 + cl][cc + g4*4];
#pragma unroll
            for (int k = 0; k < 4; k++) {
#pragma unroll
                for (int ky = 0; ky < 3; ky++) {
#pragma unroll
                    for (int kx = 0; kx < 3; kx++) {
                        float wv = ((const float*)&wv4[ky*3 + kx])[k];
                        h0 = fmaf(wv, ((const float*)&fr4[ky][kx + 0])[k], h0);
                        h1 = fmaf(wv, ((const float*)&fr4[ky][kx + 1])[k], h1);
                        h2 = fmaf(wv, ((const float*)&fr4[ky][kx + 2])[k], h2);
                        h3 = fmaf(wv, ((const float*)&fr4[ky][kx + 3])[k], h3);
                    }
                }
            }
        }
    }

    float sc = bns[c], sh = bnsh[c];
    {
        float v0 = fmaf(h0, sc, sh); hl[w*4 + 0][c] = v0 > 0.f ? v0 : 0.f;
        float v1 = fmaf(h1, sc, sh); hl[w*4 + 1][c] = v1 > 0.f ? v1 : 0.f;
        float v2 = fmaf(h2, sc, sh); hl[w*4 + 2][c] = v2 > 0.f ? v2 : 0.f;
        float v3 = fmaf(h3, sc, sh); hl[w*4 + 3][c] = v3 > 0.f ? v3 : 0.f;
    }
    __syncthreads();

    float l0 = b2[c], l1 = l0, l2 = l0, l3 = l0;
    for (int c2 = 0; c2 < C_; c2++) {
        float wv = w2t[c2*D_ + c];
        l0 = fmaf(wv, hl[w*4 + 0][c2], l0);
        l1 = fmaf(wv, hl[w*4 + 1][c2], l1);
        l2 = fmaf(wv, hl[w*4 + 2][c2], l2);
        l3 = fmaf(wv, hl[w*4 + 3][c2], l3);
    }

    float lv[4] = {l0, l1, l2, l3};
#pragma unroll
    for (int p = 0; p < 4; p++) {
        float l = lv[p];
        float m = l;
        for (int off = 32; off; off >>= 1) m = fmaxf(m, __shfl_xor(m, off));
        float e = expf(l - m);
        float s = e;
        for (int off = 32; off; off >>= 1) s += __shfl_xor(s, off);
        probs[((size_t)bn*PIX_ + y*FW_ + x0 + p)*D_ + c] = e / s;
    }
}

// ---------------- geometry: cell for point i (f32 chain, validated r4) ------
__device__ __forceinline__ int compute_cell(int i, const float* __restrict__ kinv,
                                            const float* __restrict__ ext) {
#pragma clang fp contract(off)
    int x  = i % FW_;
    int y  = (i / FW_) % FH_;
    int d  = (i / PIX_) % D_;
    int bn = i / PPBN;

    const float* kv = kinv + bn*9;
    const float* e  = ext  + bn*16;

    float u  = (x == FW_-1) ? 703.0f : (float)((double)x * (703.0/43.0));
    float vv = (float)((double)y * 17.0);
    float dd = (d == D_-1) ? 60.0f  : (float)(1.0 + (double)d * (59.0/63.0));

    float px = u * dd;
    float py = vv * dd;
    float pz = dd;

    float cx = (kv[0]*px + kv[1]*py) + kv[2]*pz;
    float cy = (kv[3]*px + kv[4]*py) + kv[5]*pz;
    float cz = (kv[6]*px + kv[7]*py) + kv[8]*pz;

    float ex = (e[0]*cx + e[1]*cy) + e[2]*cz;
    float ey = (e[4]*cx + e[5]*cy) + e[6]*cz;
    ex = ex + e[3];
    ey = ey + e[7];

    float gx = (ex + 50.0f) / 0.5f;
    float gy = (ey + 50.0f) / 0.5f;
    int ix = (int)floorf(gx);
    int iy = (int)floorf(gy);
    return (ix >= 0 && ix < BEVW && iy >= 0 && iy < BEVH) ? (iy*BEVW + ix) : -1;
}

// ---- wave run-aggregation helpers ----
__device__ __forceinline__ void run_info(int fc, int lane,
                                         bool& isLeader, int& runLen, int& lead) {
    int prev = __shfl_up(fc, 1);
    isLeader = (lane == 0) || (fc != prev);
    unsigned long long mask = __ballot(isLeader);
    unsigned long long hi = (lane == 63) ? 0ull : (mask >> (lane + 1));
    int next = hi ? (lane + 1 + __builtin_ctzll(hi)) : 64;
    runLen = next - lane;
    unsigned long long lo = mask & (~0ull >> (63 - lane));
    lead = 63 - __builtin_clzll(lo);
}

// ---------------- geom + histogram (wave-aggregated, no LDS) ----------------
__global__ __launch_bounds__(256) void geomhist_kernel(
        const float* __restrict__ ext, const float* __restrict__ kinv,
        int* __restrict__ counts) {
    int i = blockIdx.x * 256 + threadIdx.x;
    int lane = threadIdx.x & 63;
    int fc = -1;
    if (i < NPTS) {
        int cell = compute_cell(i, kinv, ext);
        if (cell >= 0) fc = (i / (PPBN * N_)) * NCELL + cell;
    }
    bool isLeader; int runLen, lead;
    run_info(fc, lane, isLeader, runLen, lead);
    if (isLeader && fc >= 0) atomicAdd(&counts[fc], runLen);
}

// ---------------- scanA: block-local scan ----------------
__global__ __launch_bounds__(256) void scanA_kernel(
        int* __restrict__ startp, int* __restrict__ cursor, int* __restrict__ bsum) {
    __shared__ int sdata[256];
    int t = threadIdx.x;
    int i = blockIdx.x * 256 + t;
    int v = (i < NBCELL) ? startp[1 + i] : 0;
    sdata[t] = v;
    __syncthreads();
#pragma unroll
    for (int off = 1; off < 256; off <<= 1) {
        int add = (t >= off) ? sdata[t - off] : 0;
        __syncthreads();
        sdata[t] += add;
        __syncthreads();
    }
    if (i < NBCELL) {
        startp[1 + i] = sdata[t];
        cursor[i]     = sdata[t] - v;
    }
    if (t == 255) bsum[blockIdx.x] = sdata[255];
}

// ---------------- scanC': re-scan bsum in LDS + apply offsets ---------------
__global__ __launch_bounds__(512) void scanC_kernel(
        int* __restrict__ startp, int* __restrict__ cursor,
        const int* __restrict__ bsum) {
    __shared__ int sdata[512];
    int t = threadIdx.x;
    int v = (t < NSCANB) ? bsum[t] : 0;
    sdata[t] = v;
    __syncthreads();
#pragma unroll
    for (int off = 1; off < 512; off <<= 1) {
        int add = (t >= off) ? sdata[t - off] : 0;
        __syncthreads();
        sdata[t] += add;
        __syncthreads();
    }
    int i = blockIdx.x * 512 + t;
    if (i >= NBCELL) return;
    int j = i >> 8;                       // which scanA block
    int off = (j == 0) ? 0 : sdata[j - 1];
    startp[1 + i] += off;
    cursor[i]     += off;
}

// ---------------- geom + scatter packed records (wave-aggregated, XCD-swz) --
// record: .x = prob bits, .y = pixg | (fc << 14)
__global__ __launch_bounds__(256) void geomscatter_kernel(
        const float* __restrict__ ext, const float* __restrict__ kinv,
        const float* __restrict__ probs,
        int* __restrict__ cursor, int2* __restrict__ plist2) {
    int blk = (blockIdx.x % NXCD) * (SCBLK/NXCD) + blockIdx.x / NXCD;
    int i = blk * 256 + threadIdx.x;
    int lane = threadIdx.x & 63;
    int fc = -1, pixg = 0;
    float pr = 0.f;
    if (i < NPTS) {
        int cell = compute_cell(i, kinv, ext);
        if (cell >= 0) {
            int pix = i % PIX_;
            int d   = (i / PIX_) % D_;
            int bn  = i / PPBN;
            fc   = (bn / N_) * NCELL + cell;
            pixg = bn*PIX_ + pix;
            pr   = probs[(size_t)pixg*D_ + d];
        }
    }
    bool isLeader; int runLen, lead;
    run_info(fc, lane, isLeader, runLen, lead);
    int base = 0;
    if (isLeader && fc >= 0) base = atomicAdd(&cursor[fc], runLen);
    base = __shfl(base, lead);
    if (fc >= 0)
        plist2[base + (lane - lead)] = make_int2(__float_as_int(pr),
                                                 pixg | (fc << 14));
}

// ---- 4-way ILP cell accumulation: 4 independent FMA chains, loads batched --
__device__ __forceinline__ float cell_accum(
        const int2* __restrict__ plist2, const float* __restrict__ feat_t,
        int q0, int q1, int lane) {
    float a0 = 0.f, a1 = 0.f, a2 = 0.f, a3 = 0.f;
    int q = q0;
    for (; q + 4 <= q1; q += 4) {
        int2 r0 = plist2[q];
        int2 r1 = plist2[q + 1];
        int2 r2 = plist2[q + 2];
        int2 r3 = plist2[q + 3];
        float f0 = feat_t[(size_t)(r0.y & 0x3FFF)*C_ + lane];
        float f1 = feat_t[(size_t)(r1.y & 0x3FFF)*C_ + lane];
        float f2 = feat_t[(size_t)(r2.y & 0x3FFF)*C_ + lane];
        float f3 = feat_t[(size_t)(r3.y & 0x3FFF)*C_ + lane];
        a0 = fmaf(__int_as_float(r0.x), f0, a0);
        a1 = fmaf(__int_as_float(r1.x), f1, a1);
        a2 = fmaf(__int_as_float(r2.x), f2, a2);
        a3 = fmaf(__int_as_float(r3.x), f3, a3);
    }
    for (; q < q1; q++) {
        int2 r = plist2[q];
        a0 = fmaf(__int_as_float(r.x),
                  feat_t[(size_t)(r.y & 0x3FFF)*C_ + lane], a0);
    }
    return (a0 + a1) + (a2 + a3);
}

// ---------------- gather4s: staged (cell-major out_t, coalesced flushes) ----
__global__ __launch_bounds__(256) void gather4s_kernel(
        const float* __restrict__ feat_t, const int* __restrict__ startp,
        const int2* __restrict__ plist2, float* __restrict__ out_t) {
    int blk  = (blockIdx.x % NXCD) * GCHUNK + blockIdx.x / NXCD;
    int gid  = blk * 256 + threadIdx.x;
    int W    = gid >> 6;
    int lane = gid & 63;
    int total = startp[NBCELL];
    int p0 = W * PPW;
    if (p0 >= total) return;
    int pe = min(p0 + PPW, total);
    int p  = p0;

    // head: cell continuing from a previous wave's range
    {
        int2 r = plist2[p0];
        int fc = ((unsigned)r.y) >> 14;
        int cs = startp[fc], ce = startp[fc + 1];
        if (cs < p0) {
            if (ce - cs > 2*PPW) {        // big: process our slice
                float acc = cell_accum(plist2, feat_t, p0, min(pe, ce), lane);
                atomicAdd(out_t + (size_t)fc*C_ + lane, acc);
            }
            p = ce;                        // small: skip (owned upstream)
        }
    }
    // cells starting in [p, pe)
    while (p < pe) {
        int2 r = plist2[p];
        int fc = ((unsigned)r.y) >> 14;
        int ce = startp[fc + 1];
        bool big = (ce - p > 2*PPW);
        int b2 = big ? min(ce, pe) : ce;   // small may extend past pe (owned)
        float acc = cell_accum(plist2, feat_t, p, b2, lane);
        float* addr = out_t + (size_t)fc*C_ + lane;   // 256B contiguous/wave
        if (big) atomicAdd(addr, acc);
        else     *addr = acc;
        p = ce;
    }
}

// ---------------- transT: out_t[fc][chan] -> out[b][chan][cell] -------------
__global__ __launch_bounds__(256) void transT_kernel(
        const float* __restrict__ out_t, float* __restrict__ out) {
    __shared__ float lds[64][65];
    int blk   = blockIdx.x;               // 0..1249
    int b     = blk / (NCELL/64);         // 625 tiles per batch
    int cell0 = (blk % (NCELL/64)) * 64;
    int t     = threadIdx.x;
    int lane  = t & 63;
    int r0    = t >> 6;
    size_t fcb = (size_t)b*NCELL + cell0;
#pragma unroll
    for (int k = 0; k < 16; k++) {
        int r = r0 + 4*k;                 // cell offset in tile
        lds[r][lane] = out_t[(fcb + r)*C_ + lane];
    }
    __syncthreads();
#pragma unroll
    for (int k = 0; k < 16; k++) {
        int ch = r0 + 4*k;
        out[((size_t)(b*C_ + ch))*NCELL + cell0 + lane] = lds[lane][ch];
    }
}

// ---------------- gather4d: direct-write fallback (r19, proven) -------------
__global__ __launch_bounds__(256) void gather4d_kernel(
        const float* __restrict__ feat_t, const int* __restrict__ startp,
        const int2* __restrict__ plist2, float* __restrict__ out) {
    int blk  = (blockIdx.x % NXCD) * GCHUNK + blockIdx.x / NXCD;
    int gid  = blk * 256 + threadIdx.x;
    int W    = gid >> 6;
    int lane = gid & 63;
    int total = startp[NBCELL];
    int p0 = W * PPW;
    if (p0 >= total) return;
    int pe = min(p0 + PPW, total);
    int p  = p0;

    {
        int2 r = plist2[p0];
        int fc = ((unsigned)r.y) >> 14;
        int cs = startp[fc], ce = startp[fc + 1];
        if (cs < p0) {
            if (ce - cs > 2*PPW) {
                float acc = cell_accum(plist2, feat_t, p0, min(pe, ce), lane);
                int bb   = fc >= NCELL;
                int cell = fc - bb*NCELL;
                atomicAdd(out + ((size_t)(bb*C_ + lane))*NCELL + cell, acc);
            }
            p = ce;
        }
    }
    while (p < pe) {
        int2 r = plist2[p];
        int fc = ((unsigned)r.y) >> 14;
        int ce = startp[fc + 1];
        bool big = (ce - p > 2*PPW);
        int b2 = big ? min(ce, pe) : ce;
        float acc = cell_accum(plist2, feat_t, p, b2, lane);
        int bb   = fc >= NCELL;
        int cell = fc - bb*NCELL;
        float* addr = out + ((size_t)(bb*C_ + lane))*NCELL + cell;
        if (big) atomicAdd(addr, acc);
        else     *addr = acc;
        p = ce;
    }
}

extern "C" void kernel_launch(void* const* d_in, const int* in_sizes, int n_in,
                              void* d_out, int out_size, void* d_ws, size_t ws_size,
                              hipStream_t stream) {
    const float* feat  = (const float*)d_in[0];
    const float* intr  = (const float*)d_in[1];
    const float* ext   = (const float*)d_in[2];
    const float* w1    = (const float*)d_in[3];
    const float* b1    = (const float*)d_in[4];
    const float* gamma = (const float*)d_in[5];
    const float* beta  = (const float*)d_in[6];
    const float* rmean = (const float*)d_in[7];
    const float* rvar  = (const float*)d_in[8];
    const float* w2    = (const float*)d_in[9];
    const float* b2    = (const float*)d_in[10];
    float* out = (float*)d_out;
    (void)in_sizes; (void)n_in; (void)out_size;

    // workspace layout (plist2 first for 8B alignment)
    int2*  plist2 = (int2*)d_ws;                    // NPTS int2 = 4.33 MB
    float* w1t    = (float*)(plist2 + NPTS);        // 36864
    float* w2t    = w1t + C_*C_*9;                  // 4096
    float* bns    = w2t + D_*C_;                    // 64
    float* bnsh   = bns + C_;                       // 64
    float* kinv   = bnsh + C_;                      // 108
    float* probs  = kinv + BN_*9;                   // 540672
    float* feat_t = probs + NPTS;                   // 540672
    int*   startp = (int*)(feat_t + NPTS);          // 80001
    int*   cursor = startp + (NBCELL + 1);          // 80000
    int*   bsum   = cursor + NBCELL;                // 313
    float* out_t  = (float*)(bsum + NSCANB);        // NBCELL*C_ = 20.5 MB
    size_t need   = (size_t)((char*)(out_t + (size_t)NBCELL*C_) - (char*)d_ws);
    bool staged   = (ws_size >= need);

    float* zt = staged ? out_t : out;   // zero target in setup

    setup_kernel<<<NB_SETUP, 256, 0, stream>>>(feat, w1, w2, gamma, beta,
                                               rmean, rvar, intr, zt, startp,
                                               w1t, w2t, bns, bnsh, kinv, feat_t);
    enc_kernel<<<528, 256, 0, stream>>>(feat_t, w1t, w2t, bns, bnsh, b1, b2, probs);
    geomhist_kernel<<<NPTS/256, 256, 0, stream>>>(ext, kinv, startp + 1);
    scanA_kernel<<<NSCANB, 256, 0, stream>>>(startp, cursor, bsum);
    scanC_kernel<<<(NBCELL + 511)/512, 512, 0, stream>>>(startp, cursor, bsum);
    geomscatter_kernel<<<SCBLK, 256, 0, stream>>>(ext, kinv, probs, cursor, plist2);
    if (staged) {
        gather4s_kernel<<<GBLK, 256, 0, stream>>>(feat_t, startp, plist2, out_t);
        transT_kernel<<<NBCELL/64, 256, 0, stream>>>(out_t, out);
    } else {
        gather4d_kernel<<<GBLK, 256, 0, stream>>>(feat_t, startp, plist2, out);
    }
}

// Round 22
// 166.310 us; speedup vs baseline: 1.3167x; 1.0606x over previous
//
#include <hip/hip_runtime.h>
#include <math.h>

#define B_   2
#define N_   6
#define C_   64
#define D_   64
#define FH_  16
#define FW_  44
#define BN_  (B_*N_)              // 12
#define PIX_ (FH_*FW_)            // 704
#define NPIX (BN_*PIX_)           // 8448
#define NPTS (BN_*D_*PIX_)        // 540672
#define PPBN (D_*PIX_)            // 45056 points per (b,n) image
#define BEVH 200
#define BEVW 200
#define NCELL (BEVH*BEVW)         // 40000
#define NBCELL (B_*NCELL)         // 80000
#define NSCANB ((NBCELL + 255)/256)  // 313 scan blocks
#define PPW  32                   // points per wave in gather (r21: 64)
#define GBLK (NPTS/(PPW*4))       // 4224 gather blocks (4 waves each)
#define NXCD 8
#define GCHUNK (GBLK/NXCD)        // 528 (4224 % 8 == 0 -> bijective swizzle)
#define SCBLK (NPTS/256)          // 2112 scatter blocks
// record pack: pixg (14 bits, max 8447) | fc << 14 (17 bits, max 79999) -> <2^31

// setup mega-kernel block ranges
#define NB_ZOUT 5000              // zero target: 5.12M f32 = 1.28M float4
#define NB_ZSP  313               // startp zero (80001 ints)
#define NB_TW   160               // weight transposes (40960 elems)
#define NB_PREP 1                 // BN affine + Kinv
#define NB_FT   132               // feat transpose
#define NB_SETUP (NB_ZOUT + NB_ZSP + NB_TW + NB_PREP + NB_FT)   // 5606

// ---------------- setup: zero zt + zero startp + transW + prep + featT -----
// w1t layout (bank-conflict-free b128 enc reads):
//   [cin-chunk(4)][tap(9)][g4 = (cin%16)/4 (4)][cout(64)][cin%4 (4)]
__global__ __launch_bounds__(256) void setup_kernel(
        const float* __restrict__ feat, const float* __restrict__ w1,
        const float* __restrict__ w2,
        const float* __restrict__ gamma, const float* __restrict__ beta,
        const float* __restrict__ rmean, const float* __restrict__ rvar,
        const float* __restrict__ intr,
        float* __restrict__ zt, int* __restrict__ startp,
        float* __restrict__ w1t, float* __restrict__ w2t,
        float* __restrict__ bns, float* __restrict__ bnsh,
        float* __restrict__ kinv, float* __restrict__ feat_t) {
#pragma clang fp contract(off)
    __shared__ float lds[64][65];
    int blk = blockIdx.x;
    int t   = threadIdx.x;

    if (blk < NB_ZOUT) {
        ((float4*)zt)[blk*256 + t] = float4{0.f, 0.f, 0.f, 0.f};
        return;
    }
    blk -= NB_ZOUT;
    if (blk < NB_ZSP) {
        int i = blk*256 + t;
        if (i < NBCELL + 1) startp[i] = 0;
        return;
    }
    blk -= NB_ZSP;
    if (blk < NB_TW) {
        int idx = blk*256 + t;
        if (idx < C_*C_*9) {
            int cout  = idx / (C_*9);
            int r     = idx % (C_*9);
            int cin   = r / 9;
            int tap   = r % 9;
            int chunk = cin >> 4;
            int g4    = (cin & 15) >> 2;
            int l4    = cin & 3;
            w1t[((((chunk*9 + tap)*4 + g4)*64 + cout)*4) + l4] = w1[idx];
        } else if (idx < C_*C_*9 + D_*C_) {
            int j = idx - C_*C_*9;
            int d = j / C_, c = j % C_;
            w2t[c*D_ + d] = w2[j];
        }
        return;
    }
    blk -= NB_TW;
    if (blk < NB_PREP) {
        if (t < C_) {
            float s = gamma[t] / sqrtf(rvar[t] + 1e-5f);
            bns[t]  = s;
            bnsh[t] = beta[t] - rmean[t] * s;
        }
        if (t < BN_) {
            const float* K = intr + t*9;
            float A[3][3];
            for (int r = 0; r < 3; r++)
                for (int cc = 0; cc < 3; cc++) A[r][cc] = K[r*3 + cc];
            int ipiv[3];
            // sgetf2
            for (int j = 0; j < 3; j++) {
                int p = j; float mx = fabsf(A[j][j]);
                for (int i = j+1; i < 3; i++) {
                    float v = fabsf(A[i][j]);
                    if (v > mx) { mx = v; p = i; }
                }
                ipiv[j] = p;
                if (p != j)
                    for (int k = 0; k < 3; k++) { float tm = A[j][k]; A[j][k] = A[p][k]; A[p][k] = tm; }
                float rpiv = 1.0f / A[j][j];
                for (int i = j+1; i < 3; i++) A[i][j] = A[i][j] * rpiv;
                for (int k = j+1; k < 3; k++)
                    for (int i = j+1; i < 3; i++)
                        A[i][k] = A[i][k] - A[i][j] * A[j][k];
            }
            // strti2
            for (int j = 0; j < 3; j++) {
                float ajj = 1.0f / A[j][j];
                A[j][j] = ajj;
                float najj = -ajj;
                for (int jj = 0; jj < j; jj++) {
                    float temp = A[jj][j];
                    for (int i = 0; i < jj; i++) A[i][j] = A[i][j] + temp * A[i][jj];
                    A[jj][j] = A[jj][j] * A[jj][jj];
                }
                for (int i = 0; i < j; i++) A[i][j] = A[i][j] * najj;
            }
            // sgetri
            for (int j = 1; j >= 0; j--) {
                float work[3];
                for (int i = j+1; i < 3; i++) { work[i] = A[i][j]; A[i][j] = 0.0f; }
                for (int k = j+1; k < 3; k++)
                    for (int i = 0; i < 3; i++)
                        A[i][j] = A[i][j] - A[i][k] * work[k];
            }
            for (int j = 2; j >= 0; j--) {
                int p = ipiv[j];
                if (p != j)
                    for (int i = 0; i < 3; i++) { float tm = A[i][j]; A[i][j] = A[i][p]; A[i][p] = tm; }
            }
            for (int k = 0; k < 9; k++) kinv[t*9 + k] = A[k/3][k%3];
        }
        return;
    }
    blk -= NB_PREP;
    // featT: [bn][c][pix] -> [bn*704+pix][c]
    {
        int bn   = blk / 11;
        int pb   = (blk % 11) * 64;
        int lane = t & 63;
        int r0   = t >> 6;
#pragma unroll
        for (int rr = 0; rr < 16; rr++) {
            int c = r0 + 4*rr;
            lds[c][lane] = feat[((size_t)bn*C_ + c)*PIX_ + pb + lane];
        }
        __syncthreads();
#pragma unroll
        for (int rr = 0; rr < 16; rr++) {
            int pr = r0 + 4*rr;
            feat_t[((size_t)bn*PIX_ + pb + pr)*C_ + lane] = lds[lane][pr];
        }
    }
}

// ---------------- enc v6: conflict-free b128 weight reads -------------------
__global__ __launch_bounds__(256) void enc_kernel(
        const float* __restrict__ feat_t,
        const float* __restrict__ w1t, const float* __restrict__ w2t,
        const float* __restrict__ bns, const float* __restrict__ bnsh,
        const float* __restrict__ b1,  const float* __restrict__ b2,
        float* __restrict__ probs) {
    __shared__ float wlds[9*C_*16];    // 36 KB: one 16-ci weight chunk
    __shared__ float flds[36][C_];     // 9 KB: 6x6 pixel window x 64 chan
    __shared__ float hl[16][C_];       // 4 KB
    int blk = blockIdx.x;              // 0..527
    int bn  = blk / 44;
    int rem = blk % 44;
    int yt  = rem / 11;
    int xt  = rem % 11;
    int t   = threadIdx.x;
    int c   = t & 63;
    int w   = __builtin_amdgcn_readfirstlane(t >> 6);   // wave id 0..3
    int y0  = yt*4;
    int x0  = xt*4;
    int y   = y0 + w;

    // stage feature window (zero-padded halo), coalesced from feat_t
    for (int s = w; s < 36; s += 4) {
        int srow = s / 6, scol = s % 6;
        int grow = y0 - 1 + srow;
        int gcol = x0 - 1 + scol;
        float v = 0.f;
        if (grow >= 0 && grow < FH_ && gcol >= 0 && gcol < FW_)
            v = feat_t[((size_t)bn*PIX_ + grow*FW_ + gcol)*C_ + c];
        flds[s][c] = v;
    }

    float h0 = b1[c], h1 = h0, h2 = h0, h3 = h0;

    for (int cc16 = 0; cc16 < 4; cc16++) {
        __syncthreads();               // covers flds (1st iter) + wlds reuse
        {
            const float4* s4 = (const float4*)(w1t + cc16*(9*C_*16));
            float4* d4 = (float4*)wlds;
#pragma unroll
            for (int i = 0; i < 9; i++)
                d4[t + 256*i] = s4[t + 256*i];
        }
        __syncthreads();
        int cc = cc16*16;
#pragma unroll
        for (int g4 = 0; g4 < 4; g4++) {
            float4 wv4[9];
#pragma unroll
            for (int tap = 0; tap < 9; tap++)
                wv4[tap] = *(const float4*)&wlds[((tap*4 + g4)*64 + c)*4];
            float4 fr4[3][6];
#pragma unroll
            for (int r = 0; r < 3; r++)
#pragma unroll
                for (int cl = 0; cl < 6; cl++)
                    fr4[r][cl] = *(const float4*)&flds[(w + r)*6 + cl][cc + g4*4];
#pragma unroll
            for (int k = 0; k < 4; k++) {
#pragma unroll
                for (int ky = 0; ky < 3; ky++) {
#pragma unroll
                    for (int kx = 0; kx < 3; kx++) {
                        float wv = ((const float*)&wv4[ky*3 + kx])[k];
                        h0 = fmaf(wv, ((const float*)&fr4[ky][kx + 0])[k], h0);
                        h1 = fmaf(wv, ((const float*)&fr4[ky][kx + 1])[k], h1);
                        h2 = fmaf(wv, ((const float*)&fr4[ky][kx + 2])[k], h2);
                        h3 = fmaf(wv, ((const float*)&fr4[ky][kx + 3])[k], h3);
                    }
                }
            }
        }
    }

    float sc = bns[c], sh = bnsh[c];
    {
        float v0 = fmaf(h0, sc, sh); hl[w*4 + 0][c] = v0 > 0.f ? v0 : 0.f;
        float v1 = fmaf(h1, sc, sh); hl[w*4 + 1][c] = v1 > 0.f ? v1 : 0.f;
        float v2 = fmaf(h2, sc, sh); hl[w*4 + 2][c] = v2 > 0.f ? v2 : 0.f;
        float v3 = fmaf(h3, sc, sh); hl[w*4 + 3][c] = v3 > 0.f ? v3 : 0.f;
    }
    __syncthreads();

    float l0 = b2[c], l1 = l0, l2 = l0, l3 = l0;
    for (int c2 = 0; c2 < C_; c2++) {
        float wv = w2t[c2*D_ + c];
        l0 = fmaf(wv, hl[w*4 + 0][c2], l0);
        l1 = fmaf(wv, hl[w*4 + 1][c2], l1);
        l2 = fmaf(wv, hl[w*4 + 2][c2], l2);
        l3 = fmaf(wv, hl[w*4 + 3][c2], l3);
    }

    float lv[4] = {l0, l1, l2, l3};
#pragma unroll
    for (int p = 0; p < 4; p++) {
        float l = lv[p];
        float m = l;
        for (int off = 32; off; off >>= 1) m = fmaxf(m, __shfl_xor(m, off));
        float e = expf(l - m);
        float s = e;
        for (int off = 32; off; off >>= 1) s += __shfl_xor(s, off);
        probs[((size_t)bn*PIX_ + y*FW_ + x0 + p)*D_ + c] = e / s;
    }
}

// ---------------- geometry: cell for point i (f32 chain, validated r4) ------
__device__ __forceinline__ int compute_cell(int i, const float* __restrict__ kinv,
                                            const float* __restrict__ ext) {
#pragma clang fp contract(off)
    int x  = i % FW_;
    int y  = (i / FW_) % FH_;
    int d  = (i / PIX_) % D_;
    int bn = i / PPBN;

    const float* kv = kinv + bn*9;
    const float* e  = ext  + bn*16;

    float u  = (x == FW_-1) ? 703.0f : (float)((double)x * (703.0/43.0));
    float vv = (float)((double)y * 17.0);
    float dd = (d == D_-1) ? 60.0f  : (float)(1.0 + (double)d * (59.0/63.0));

    float px = u * dd;
    float py = vv * dd;
    float pz = dd;

    float cx = (kv[0]*px + kv[1]*py) + kv[2]*pz;
    float cy = (kv[3]*px + kv[4]*py) + kv[5]*pz;
    float cz = (kv[6]*px + kv[7]*py) + kv[8]*pz;

    float ex = (e[0]*cx + e[1]*cy) + e[2]*cz;
    float ey = (e[4]*cx + e[5]*cy) + e[6]*cz;
    ex = ex + e[3];
    ey = ey + e[7];

    float gx = (ex + 50.0f) / 0.5f;
    float gy = (ey + 50.0f) / 0.5f;
    int ix = (int)floorf(gx);
    int iy = (int)floorf(gy);
    return (ix >= 0 && ix < BEVW && iy >= 0 && iy < BEVH) ? (iy*BEVW + ix) : -1;
}

// ---- wave run-aggregation helpers ----
__device__ __forceinline__ void run_info(int fc, int lane,
                                         bool& isLeader, int& runLen, int& lead) {
    int prev = __shfl_up(fc, 1);
    isLeader = (lane == 0) || (fc != prev);
    unsigned long long mask = __ballot(isLeader);
    unsigned long long hi = (lane == 63) ? 0ull : (mask >> (lane + 1));
    int next = hi ? (lane + 1 + __builtin_ctzll(hi)) : 64;
    runLen = next - lane;
    unsigned long long lo = mask & (~0ull >> (63 - lane));
    lead = 63 - __builtin_clzll(lo);
}

// ---------------- geom + histogram (wave-aggregated, no LDS) ----------------
__global__ __launch_bounds__(256) void geomhist_kernel(
        const float* __restrict__ ext, const float* __restrict__ kinv,
        int* __restrict__ counts) {
    int i = blockIdx.x * 256 + threadIdx.x;
    int lane = threadIdx.x & 63;
    int fc = -1;
    if (i < NPTS) {
        int cell = compute_cell(i, kinv, ext);
        if (cell >= 0) fc = (i / (PPBN * N_)) * NCELL + cell;
    }
    bool isLeader; int runLen, lead;
    run_info(fc, lane, isLeader, runLen, lead);
    if (isLeader && fc >= 0) atomicAdd(&counts[fc], runLen);
}

// ---------------- scanA: block-local scan ----------------
__global__ __launch_bounds__(256) void scanA_kernel(
        int* __restrict__ startp, int* __restrict__ cursor, int* __restrict__ bsum) {
    __shared__ int sdata[256];
    int t = threadIdx.x;
    int i = blockIdx.x * 256 + t;
    int v = (i < NBCELL) ? startp[1 + i] : 0;
    sdata[t] = v;
    __syncthreads();
#pragma unroll
    for (int off = 1; off < 256; off <<= 1) {
        int add = (t >= off) ? sdata[t - off] : 0;
        __syncthreads();
        sdata[t] += add;
        __syncthreads();
    }
    if (i < NBCELL) {
        startp[1 + i] = sdata[t];
        cursor[i]     = sdata[t] - v;
    }
    if (t == 255) bsum[blockIdx.x] = sdata[255];
}

// ---------------- scanC': re-scan bsum in LDS + apply offsets ---------------
__global__ __launch_bounds__(512) void scanC_kernel(
        int* __restrict__ startp, int* __restrict__ cursor,
        const int* __restrict__ bsum) {
    __shared__ int sdata[512];
    int t = threadIdx.x;
    int v = (t < NSCANB) ? bsum[t] : 0;
    sdata[t] = v;
    __syncthreads();
#pragma unroll
    for (int off = 1; off < 512; off <<= 1) {
        int add = (t >= off) ? sdata[t - off] : 0;
        __syncthreads();
        sdata[t] += add;
        __syncthreads();
    }
    int i = blockIdx.x * 512 + t;
    if (i >= NBCELL) return;
    int j = i >> 8;                       // which scanA block
    int off = (j == 0) ? 0 : sdata[j - 1];
    startp[1 + i] += off;
    cursor[i]     += off;
}

// ---------------- geom + scatter packed records (wave-aggregated, XCD-swz) --
// record: .x = prob bits, .y = pixg | (fc << 14)
__global__ __launch_bounds__(256) void geomscatter_kernel(
        const float* __restrict__ ext, const float* __restrict__ kinv,
        const float* __restrict__ probs,
        int* __restrict__ cursor, int2* __restrict__ plist2) {
    int blk = (blockIdx.x % NXCD) * (SCBLK/NXCD) + blockIdx.x / NXCD;
    int i = blk * 256 + threadIdx.x;
    int lane = threadIdx.x & 63;
    int fc = -1, pixg = 0;
    float pr = 0.f;
    if (i < NPTS) {
        int cell = compute_cell(i, kinv, ext);
        if (cell >= 0) {
            int pix = i % PIX_;
            int d   = (i / PIX_) % D_;
            int bn  = i / PPBN;
            fc   = (bn / N_) * NCELL + cell;
            pixg = bn*PIX_ + pix;
            pr   = probs[(size_t)pixg*D_ + d];
        }
    }
    bool isLeader; int runLen, lead;
    run_info(fc, lane, isLeader, runLen, lead);
    int base = 0;
    if (isLeader && fc >= 0) base = atomicAdd(&cursor[fc], runLen);
    base = __shfl(base, lead);
    if (fc >= 0)
        plist2[base + (lane - lead)] = make_int2(__float_as_int(pr),
                                                 pixg | (fc << 14));
}

// ---- 8/4-wide ILP cell accumulation: independent FMA chains, loads batched --
__device__ __forceinline__ float cell_accum(
        const int2* __restrict__ plist2, const float* __restrict__ feat_t,
        int q0, int q1, int lane) {
    float a0 = 0.f, a1 = 0.f, a2 = 0.f, a3 = 0.f;
    float a4 = 0.f, a5 = 0.f, a6 = 0.f, a7 = 0.f;
    int q = q0;
    for (; q + 8 <= q1; q += 8) {
        int2 r0 = plist2[q];
        int2 r1 = plist2[q + 1];
        int2 r2 = plist2[q + 2];
        int2 r3 = plist2[q + 3];
        int2 r4 = plist2[q + 4];
        int2 r5 = plist2[q + 5];
        int2 r6 = plist2[q + 6];
        int2 r7 = plist2[q + 7];
        float f0 = feat_t[(size_t)(r0.y & 0x3FFF)*C_ + lane];
        float f1 = feat_t[(size_t)(r1.y & 0x3FFF)*C_ + lane];
        float f2 = feat_t[(size_t)(r2.y & 0x3FFF)*C_ + lane];
        float f3 = feat_t[(size_t)(r3.y & 0x3FFF)*C_ + lane];
        float f4 = feat_t[(size_t)(r4.y & 0x3FFF)*C_ + lane];
        float f5 = feat_t[(size_t)(r5.y & 0x3FFF)*C_ + lane];
        float f6 = feat_t[(size_t)(r6.y & 0x3FFF)*C_ + lane];
        float f7 = feat_t[(size_t)(r7.y & 0x3FFF)*C_ + lane];
        a0 = fmaf(__int_as_float(r0.x), f0, a0);
        a1 = fmaf(__int_as_float(r1.x), f1, a1);
        a2 = fmaf(__int_as_float(r2.x), f2, a2);
        a3 = fmaf(__int_as_float(r3.x), f3, a3);
        a4 = fmaf(__int_as_float(r4.x), f4, a4);
        a5 = fmaf(__int_as_float(r5.x), f5, a5);
        a6 = fmaf(__int_as_float(r6.x), f6, a6);
        a7 = fmaf(__int_as_float(r7.x), f7, a7);
    }
    for (; q + 4 <= q1; q += 4) {
        int2 r0 = plist2[q];
        int2 r1 = plist2[q + 1];
        int2 r2 = plist2[q + 2];
        int2 r3 = plist2[q + 3];
        float f0 = feat_t[(size_t)(r0.y & 0x3FFF)*C_ + lane];
        float f1 = feat_t[(size_t)(r1.y & 0x3FFF)*C_ + lane];
        float f2 = feat_t[(size_t)(r2.y & 0x3FFF)*C_ + lane];
        float f3 = feat_t[(size_t)(r3.y & 0x3FFF)*C_ + lane];
        a0 = fmaf(__int_as_float(r0.x), f0, a0);
        a1 = fmaf(__int_as_float(r1.x), f1, a1);
        a2 = fmaf(__int_as_float(r2.x), f2, a2);
        a3 = fmaf(__int_as_float(r3.x), f3, a3);
    }
    for (; q < q1; q++) {
        int2 r = plist2[q];
        a0 = fmaf(__int_as_float(r.x),
                  feat_t[(size_t)(r.y & 0x3FFF)*C_ + lane], a0);
    }
    return ((a0 + a1) + (a2 + a3)) + ((a4 + a5) + (a6 + a7));
}

// ---------------- gather4s: staged (cell-major out_t, coalesced flushes) ----
__global__ __launch_bounds__(256) void gather4s_kernel(
        const float* __restrict__ feat_t, const int* __restrict__ startp,
        const int2* __restrict__ plist2, float* __restrict__ out_t) {
    int blk  = (blockIdx.x % NXCD) * GCHUNK + blockIdx.x / NXCD;
    int gid  = blk * 256 + threadIdx.x;
    int W    = gid >> 6;
    int lane = gid & 63;
    int total = startp[NBCELL];
    int p0 = W * PPW;
    if (p0 >= total) return;
    int pe = min(p0 + PPW, total);
    int p  = p0;

    // head: cell continuing from a previous wave's range
    {
        int2 r = plist2[p0];
        int fc = ((unsigned)r.y) >> 14;
        int cs = startp[fc], ce = startp[fc + 1];
        if (cs < p0) {
            if (ce - cs > 2*PPW) {        // big: process our slice
                float acc = cell_accum(plist2, feat_t, p0, min(pe, ce), lane);
                atomicAdd(out_t + (size_t)fc*C_ + lane, acc);
            }
            p = ce;                        // small: skip (owned upstream)
        }
    }
    // cells starting in [p, pe)
    while (p < pe) {
        int2 r = plist2[p];
        int fc = ((unsigned)r.y) >> 14;
        int ce = startp[fc + 1];
        bool big = (ce - p > 2*PPW);
        int b2 = big ? min(ce, pe) : ce;   // small may extend past pe (owned)
        float acc = cell_accum(plist2, feat_t, p, b2, lane);
        float* addr = out_t + (size_t)fc*C_ + lane;   // 256B contiguous/wave
        if (big) atomicAdd(addr, acc);
        else     *addr = acc;
        p = ce;
    }
}

// ---------------- transT: out_t[fc][chan] -> out[b][chan][cell] -------------
__global__ __launch_bounds__(256) void transT_kernel(
        const float* __restrict__ out_t, float* __restrict__ out) {
    __shared__ float lds[64][65];
    int blk   = blockIdx.x;               // 0..1249
    int b     = blk / (NCELL/64);         // 625 tiles per batch
    int cell0 = (blk % (NCELL/64)) * 64;
    int t     = threadIdx.x;
    int lane  = t & 63;
    int r0    = t >> 6;
    size_t fcb = (size_t)b*NCELL + cell0;
#pragma unroll
    for (int k = 0; k < 16; k++) {
        int r = r0 + 4*k;                 // cell offset in tile
        lds[r][lane] = out_t[(fcb + r)*C_ + lane];
    }
    __syncthreads();
#pragma unroll
    for (int k = 0; k < 16; k++) {
        int ch = r0 + 4*k;
        out[((size_t)(b*C_ + ch))*NCELL + cell0 + lane] = lds[lane][ch];
    }
}

// ---------------- gather4d: direct-write fallback -------------
__global__ __launch_bounds__(256) void gather4d_kernel(
        const float* __restrict__ feat_t, const int* __restrict__ startp,
        const int2* __restrict__ plist2, float* __restrict__ out) {
    int blk  = (blockIdx.x % NXCD) * GCHUNK + blockIdx.x / NXCD;
    int gid  = blk * 256 + threadIdx.x;
    int W    = gid >> 6;
    int lane = gid & 63;
    int total = startp[NBCELL];
    int p0 = W * PPW;
    if (p0 >= total) return;
    int pe = min(p0 + PPW, total);
    int p  = p0;

    {
        int2 r = plist2[p0];
        int fc = ((unsigned)r.y) >> 14;
        int cs = startp[fc], ce = startp[fc + 1];
        if (cs < p0) {
            if (ce - cs > 2*PPW) {
                float acc = cell_accum(plist2, feat_t, p0, min(pe, ce), lane);
                int bb   = fc >= NCELL;
                int cell = fc - bb*NCELL;
                atomicAdd(out + ((size_t)(bb*C_ + lane))*NCELL + cell, acc);
            }
            p = ce;
        }
    }
    while (p < pe) {
        int2 r = plist2[p];
        int fc = ((unsigned)r.y) >> 14;
        int ce = startp[fc + 1];
        bool big = (ce - p > 2*PPW);
        int b2 = big ? min(ce, pe) : ce;
        float acc = cell_accum(plist2, feat_t, p, b2, lane);
        int bb   = fc >= NCELL;
        int cell = fc - bb*NCELL;
        float* addr = out + ((size_t)(bb*C_ + lane))*NCELL + cell;
        if (big) atomicAdd(addr, acc);
        else     *addr = acc;
        p = ce;
    }
}

extern "C" void kernel_launch(void* const* d_in, const int* in_sizes, int n_in,
                              void* d_out, int out_size, void* d_ws, size_t ws_size,
                              hipStream_t stream) {
    const float* feat  = (const float*)d_in[0];
    const float* intr  = (const float*)d_in[1];
    const float* ext   = (const float*)d_in[2];
    const float* w1    = (const float*)d_in[3];
    const float* b1    = (const float*)d_in[4];
    const float* gamma = (const float*)d_in[5];
    const float* beta  = (const float*)d_in[6];
    const float* rmean = (const float*)d_in[7];
    const float* rvar  = (const float*)d_in[8];
    const float* w2    = (const float*)d_in[9];
    const float* b2    = (const float*)d_in[10];
    float* out = (float*)d_out;
    (void)in_sizes; (void)n_in; (void)out_size;

    // workspace layout (plist2 first for 8B alignment)
    int2*  plist2 = (int2*)d_ws;                    // NPTS int2 = 4.33 MB
    float* w1t    = (float*)(plist2 + NPTS);        // 36864
    float* w2t    = w1t + C_*C_*9;                  // 4096
    float* bns    = w2t + D_*C_;                    // 64
    float* bnsh   = bns + C_;                       // 64
    float* kinv   = bnsh + C_;                      // 108
    float* probs  = kinv + BN_*9;                   // 540672
    float* feat_t = probs + NPTS;                   // 540672
    int*   startp = (int*)(feat_t + NPTS);          // 80001
    int*   cursor = startp + (NBCELL + 1);          // 80000
    int*   bsum   = cursor + NBCELL;                // 313
    float* out_t  = (float*)(bsum + NSCANB);        // NBCELL*C_ = 20.5 MB
    size_t need   = (size_t)((char*)(out_t + (size_t)NBCELL*C_) - (char*)d_ws);
    bool staged   = (ws_size >= need);

    float* zt = staged ? out_t : out;   // zero target in setup

    setup_kernel<<<NB_SETUP, 256, 0, stream>>>(feat, w1, w2, gamma, beta,
                                               rmean, rvar, intr, zt, startp,
                                               w1t, w2t, bns, bnsh, kinv, feat_t);
    enc_kernel<<<528, 256, 0, stream>>>(feat_t, w1t, w2t, bns, bnsh, b1, b2, probs);
    geomhist_kernel<<<NPTS/256, 256, 0, stream>>>(ext, kinv, startp + 1);
    scanA_kernel<<<NSCANB, 256, 0, stream>>>(startp, cursor, bsum);
    scanC_kernel<<<(NBCELL + 511)/512, 512, 0, stream>>>(startp, cursor, bsum);
    geomscatter_kernel<<<SCBLK, 256, 0, stream>>>(ext, kinv, probs, cursor, plist2);
    if (staged) {
        gather4s_kernel<<<GBLK, 256, 0, stream>>>(feat_t, startp, plist2, out_t);
        transT_kernel<<<NBCELL/64, 256, 0, stream>>>(out_t, out);
    } else {
        gather4d_kernel<<<GBLK, 256, 0, stream>>>(feat_t, startp, plist2, out);
    }
}